// Round 9
// baseline (2638.508 us; speedup 1.0000x reference)
//
#include <hip/hip_runtime.h>
#include <hip/hip_bf16.h>
#include <math.h>

#define NB 256
#define CDD 5
#define HIS 50
#define NITEMS 55
#define TT 20
#define DD 300
#define NH 16
#define VDIM 16
#define RP 256
#define QDIM 200
#define SCALEF 0.057735026918962584f   // 1/sqrt(300)

typedef __attribute__((ext_vector_type(8)))  short bf16x8;
typedef __attribute__((ext_vector_type(4)))  short short4v;
typedef __attribute__((ext_vector_type(4)))  float f32x4;
typedef __attribute__((ext_vector_type(16))) float f32x16;

#define MFMA16(a,b,c) __builtin_amdgcn_mfma_f32_16x16x32_bf16((a),(b),(c),0,0,0)
#define MFMA32(a,b,c) __builtin_amdgcn_mfma_f32_32x32x16_bf16((a),(b),(c),0,0,0)

__device__ __forceinline__ ushort f2bf(float f) {
    union { float f; unsigned u; } c; c.f = f;
    unsigned u = c.u;
    return (ushort)((u + 0x7fffu + ((u >> 16) & 1u)) >> 16);
}
__device__ __forceinline__ float bf2f(ushort h) {
    union { unsigned u; float f; } c; c.u = ((unsigned)h) << 16;
    return c.f;
}

#define XS  328
#define QS  136
#define VS  264
#define XVS 264   // fallback kernel's XVT stride
#define XV8 72    // v8 XVT stride

// ---------------------------------------------------------------------------
// prep_wqa: Wq[h][f 300][e 300] -> A-fragment-tiled bf16
//   WqA[h][et 10][ks 20][e_in 32][k_in 16], zero-padded.
// ---------------------------------------------------------------------------
__global__ __launch_bounds__(256)
void prep_wqa(const float* __restrict__ Wq, ushort* __restrict__ WqA)
{
    const int TOT = 16 * 102400;
    for (int idx = blockIdx.x * 256 + threadIdx.x; idx < TOT; idx += gridDim.x * 256) {
        const int h  = idx / 102400;
        int r  = idx - h * 102400;
        const int et = r / 10240;  r -= et * 10240;
        const int ks = r / 512;    r -= ks * 512;
        const int ei = r >> 4, ki = r & 15;
        const int e = et * 32 + ei, f = ks * 16 + ki;
        const float v = (e < 300 && f < 300) ? Wq[(h * 300 + f) * 300 + e] : 0.f;
        WqA[idx] = f2bf(v);
    }
}

// ---------------------------------------------------------------------------
// transpose_pad: dst[slice][c][r] = src[slice][r][c], bf16, padded
// ---------------------------------------------------------------------------
__global__ __launch_bounds__(256)
void transpose_pad(const float* __restrict__ src, ushort* __restrict__ dst,
                   int R, int C, int src_ld, int Rp, int Cv,
                   long src_ss, long dst_ss)
{
    __shared__ float T[32][33];
    const int r0 = blockIdx.x * 32;
    const int c0 = blockIdx.y * 32;
    const float* s = src + blockIdx.z * src_ss;
    ushort* d = dst + blockIdx.z * dst_ss;
    const int i = threadIdx.x >> 3;
    const int j4 = (threadIdx.x & 7) * 4;
#pragma unroll
    for (int t = 0; t < 4; ++t) {
        const int r = r0 + i, c = c0 + j4 + t;
        T[i][j4 + t] = (r < R && c < C) ? s[(long)r * src_ld + c] : 0.f;
    }
    __syncthreads();
#pragma unroll
    for (int t = 0; t < 4; ++t) {
        const int orow = c0 + i;
        const int ocol = r0 + j4 + t;
        if (orow < Cv && ocol < Rp)
            d[(long)orow * Rp + ocol] = f2bf(T[j4 + t][i]);
    }
}

// ---------------------------------------------------------------------------
// EV = E * Wv (all vocab):  EV[v][256] bf16.  64 rows per block.
// ---------------------------------------------------------------------------
__global__ __launch_bounds__(256)
void prep_ev(const float* __restrict__ E, const ushort* __restrict__ WvT,
             ushort* __restrict__ EV)
{
    __shared__ ushort Ebf[64 * XS];
    const int tid = threadIdx.x;
    const int r0 = blockIdx.x * 64;
    for (int i = tid; i < (64 * XS) / 2; i += 256) ((unsigned*)Ebf)[i] = 0u;
    __syncthreads();
    for (int idx = tid; idx < 64 * 75; idx += 256) {
        const int row = idx / 75, q = idx - row * 75;
        const int vr = r0 + row;
        if (vr < 50000) {
            const float4 v = ((const float4*)E)[(long)vr * 75 + q];
            short4v p;
            p.x = (short)f2bf(v.x); p.y = (short)f2bf(v.y);
            p.z = (short)f2bf(v.z); p.w = (short)f2bf(v.w);
            *(short4v*)(Ebf + row * XS + q * 4) = p;
        }
    }
    __syncthreads();
    const int w = tid >> 6, l15 = tid & 15, lhi = (tid >> 4) & 3;
    const f32x4 z4 = {0.f, 0.f, 0.f, 0.f};
    for (int n = 0; n < 16; ++n) {
        f32x4 acc = z4;
#pragma unroll
        for (int ks = 0; ks < 10; ++ks) {
            const int off = ks * 32 + lhi * 8;
            const bf16x8 A = *(const bf16x8*)(Ebf + (16 * w + l15) * XS + off);
            const bf16x8 B = *(const bf16x8*)(WvT + (16 * n + l15) * 320 + off);
            acc = MFMA16(A, B, acc);
        }
#pragma unroll
        for (int r = 0; r < 4; ++r) {
            const int row = r0 + 16 * w + lhi * 4 + r;
            if (row < 50000) EV[(long)row * 256 + 16 * n + l15] = f2bf(acc[r]);
        }
    }
}

__device__ __forceinline__ f32x16 zero16() {
    f32x16 z;
#pragma unroll
    for (int i = 0; i < 16; ++i) z[i] = 0.f;
    return z;
}

// ---------------------------------------------------------------------------
// qc_et2: one wave, one 32-e tile, 2 m-tiles over 40 rows (m=1 rows<8 valid).
// ---------------------------------------------------------------------------
__device__ __forceinline__ void qc_et2(const ushort* __restrict__ WqAh,
                                       const ushort* Xl, ushort* Qcl,
                                       int et, int jcol, int l31, int hi)
{
    f32x16 acc0 = zero16(), acc1 = zero16();
    const ushort* abase = WqAh + (et * 20) * 512 + l31 * 16 + hi * 8;
    bf16x8 Abuf[5];
#pragma unroll
    for (int i = 0; i < 5; ++i) Abuf[i] = *(const bf16x8*)(abase + i * 512);
    const int brow0 = l31;                       // rows 0..31 (valid)
    const int brow1 = 32 + (l31 & 7);            // rows 32..39 (l31>=8 lanes read in-range garbage)
    __builtin_amdgcn_s_setprio(1);
#pragma unroll
    for (int ks = 0; ks < 20; ++ks) {
        const bf16x8 A = Abuf[ks % 5];
        const int xoff = ks * 16 + hi * 8;
        const bf16x8 B0 = *(const bf16x8*)(Xl + brow0 * XS + xoff);
        acc0 = MFMA32(A, B0, acc0);
        const bf16x8 B1 = *(const bf16x8*)(Xl + brow1 * XS + xoff);
        acc1 = MFMA32(A, B1, acc1);
        if (ks + 5 < 20) Abuf[ks % 5] = *(const bf16x8*)(abase + (ks + 5) * 512);
    }
    __builtin_amdgcn_s_setprio(0);
#pragma unroll
    for (int m = 0; m < 2; ++m) {
        f32x16 a = (m == 0) ? acc0 : acc1;
        if (m == 1 && l31 >= 8) continue;        // rows >= 40 not stored
        ushort* qrow = Qcl + (32 * m + l31) * QS + jcol * 32;
#pragma unroll
        for (int g = 0; g < 4; ++g) {
            short4v p;
            p.x = (short)f2bf(a[4 * g + 0]);
            p.y = (short)f2bf(a[4 * g + 1]);
            p.z = (short)f2bf(a[4 * g + 2]);
            p.w = (short)f2bf(a[4 * g + 3]);
            *(short4v*)(qrow + 8 * g + 4 * hi) = p;
        }
    }
}

// s_chunk with clamped rows (garbage lanes read in-range rows, results masked)
template<int NT>
__device__ __forceinline__ void s_chunk8(const ushort* Xl, const ushort* Qcl,
                                         f32x16& sacc, int ebase, int i20,
                                         int l31, int hi)
{
    const int rr = i20 + ((l31 < 20) ? l31 : (l31 - 20));   // < 40 always
    const ushort* xr = Xl + rr * XS + ebase + hi * 8;
    const ushort* qr = Qcl + rr * QS + hi * 8;
#pragma unroll
    for (int kst = 0; kst < 2 * NT; ++kst) {
        const bf16x8 A = *(const bf16x8*)(xr + kst * 16);
        const bf16x8 B = *(const bf16x8*)(qr + kst * 16);
        sacc = MFMA32(A, B, sacc);
    }
}

// ---------------------------------------------------------------------------
// Word encoder v8: 2 items/block, 128 threads (2 waves), 39.7 KB LDS
// -> 4 independent blocks/CU. Requires EV table.
// ---------------------------------------------------------------------------
#define POOLE8 19712   // ushorts: Xbf 13120 | Qc 5440 | XVT 1152

__global__ __launch_bounds__(128, 2)
void word_encoder_v8(const int* __restrict__ cddT, const int* __restrict__ hisT,
                     const float* __restrict__ E,
                     const ushort* __restrict__ WqA, const ushort* __restrict__ EV,
                     const ushort* __restrict__ WkT,
                     const float* __restrict__ bk, const float* __restrict__ qv,
                     float* __restrict__ cddR, float* __restrict__ hisR)
{
    __shared__ ushort pool[POOLE8];
    __shared__ float  wrf[40];
    __shared__ int    toks[40];
    ushort* Xbf = pool;            // 40 x XS
    ushort* Qc  = pool + 13120;    // 40 x QS
    ushort* XVT = pool + 18560;    // 16 x XV8 (cols t>=20 in each item slot stay 0)

    const int tid = threadIdx.x;
    const int w   = tid >> 6;          // wave = item (0..1)
    const int l31 = tid & 31;
    const int hi  = (tid >> 5) & 1;
    const int l15 = tid & 15;
    const int lhi = (tid >> 4) & 3;
    const f32x4 z4 = {0.f, 0.f, 0.f, 0.f};
    const int item = w;
    const int i20  = item * 20;

    for (int i = tid; i < 13120 / 2; i += 128) ((unsigned*)Xbf)[i] = 0u;
    for (int i = tid; i < 1152 / 2; i += 128) ((unsigned*)XVT)[i] = 0u;
    if (tid < 40) {
        wrf[tid] = 0.f;
        const int it_l = tid / 20, t = tid - it_l * 20;
        const int gi = blockIdx.x * 2 + it_l;
        const int b = gi / NITEMS, it = gi - b * NITEMS;
        toks[tid] = (it < CDD) ? cddT[(b * CDD + it) * TT + t]
                               : hisT[(b * HIS + (it - CDD)) * TT + t];
    }
    __syncthreads();

    // ---- embeddings -> bf16 LDS (40 rows) ----
    for (int idx = tid; idx < 40 * 38; idx += 128) {
        const int r = idx / 38, g = idx - r * 38;
        const long base = (long)toks[r] * 300 + g * 8;
        short4v p0, p1;
        if (g < 37) {
            const float4 v0 = *(const float4*)(E + base);
            const float4 v1 = *(const float4*)(E + base + 4);
            p0.x = (short)f2bf(v0.x); p0.y = (short)f2bf(v0.y);
            p0.z = (short)f2bf(v0.z); p0.w = (short)f2bf(v0.w);
            p1.x = (short)f2bf(v1.x); p1.y = (short)f2bf(v1.y);
            p1.z = (short)f2bf(v1.z); p1.w = (short)f2bf(v1.w);
        } else {
            const float4 v0 = *(const float4*)(E + base);
            p0.x = (short)f2bf(v0.x); p0.y = (short)f2bf(v0.y);
            p0.z = (short)f2bf(v0.z); p0.w = (short)f2bf(v0.w);
            p1.x = 0; p1.y = 0; p1.z = 0; p1.w = 0;
        }
        *(short4v*)(Xbf + r * XS + g * 8) = p0;
        *(short4v*)(Xbf + r * XS + g * 8 + 4) = p1;
    }
    __syncthreads();

    // per-item Vl packed accumulators: 16 heads x 4 u32
    unsigned va0=0,va1=0,va2=0,va3=0,va4=0,va5=0,va6=0,va7=0;
    unsigned va8=0,va9=0,va10=0,va11=0,va12=0,va13=0,va14=0,va15=0;
    unsigned vb0=0,vb1=0,vb2=0,vb3=0,vb4=0,vb5=0,vb6=0,vb7=0;
    unsigned vb8=0,vb9=0,vb10=0,vb11=0,vb12=0,vb13=0,vb14=0,vb15=0;
    unsigned vc0=0,vc1=0,vc2=0,vc3=0,vc4=0,vc5=0,vc6=0,vc7=0;
    unsigned vc8=0,vc9=0,vc10=0,vc11=0,vc12=0,vc13=0,vc14=0,vc15=0;
    unsigned vd0=0,vd1=0,vd2=0,vd3=0,vd4=0,vd5=0,vd6=0,vd7=0;
    unsigned vd8=0,vd9=0,vd10=0,vd11=0,vd12=0,vd13=0,vd14=0,vd15=0;

#pragma unroll 1
    for (int h = 0; h < 16; ++h) {
        const ushort* WqAh = WqA + h * 102400;
        f32x16 sacc = zero16();

        // ---- P0: XVT fill (tid<80) + qc chunk0 (et 2w, 2w+1) ----
        if (tid < 80) {
            const int tok = tid >> 1, half = tid & 1;
            const int it2 = tok / 20, lt = tok - it2 * 20;
            const ushort4* src = (const ushort4*)(EV + (long)toks[tok] * 256 + h * 16 + half * 8);
            const ushort4 a = src[0], b2 = src[1];
            ushort* dst0 = XVT + (half * 8) * XV8 + it2 * 32 + lt;
            dst0[0 * XV8] = a.x;  dst0[1 * XV8] = a.y;
            dst0[2 * XV8] = a.z;  dst0[3 * XV8] = a.w;
            dst0[4 * XV8] = b2.x; dst0[5 * XV8] = b2.y;
            dst0[6 * XV8] = b2.z; dst0[7 * XV8] = b2.w;
        }
        qc_et2(WqAh, Xbf, Qc, 2 * w,     2 * w,     l31, hi);
        qc_et2(WqAh, Xbf, Qc, 2 * w + 1, 2 * w + 1, l31, hi);
        __syncthreads();
        s_chunk8<4>(Xbf, Qc, sacc, 0, i20, l31, hi);
        __syncthreads();

        // ---- chunk1 (et 4..7) ----
        qc_et2(WqAh, Xbf, Qc, 4 + 2 * w,     2 * w,     l31, hi);
        qc_et2(WqAh, Xbf, Qc, 4 + 2 * w + 1, 2 * w + 1, l31, hi);
        __syncthreads();
        s_chunk8<4>(Xbf, Qc, sacc, 128, i20, l31, hi);
        __syncthreads();

        // ---- chunk2 (et 8..9) ----
        qc_et2(WqAh, Xbf, Qc, 8 + w, w, l31, hi);
        __syncthreads();
        s_chunk8<2>(Xbf, Qc, sacc, 256, i20, l31, hi);
        __syncthreads();

        // ---- softmax over t per s=l31, in registers ----
        float pv[16];
        float vmax = -1e30f;
#pragma unroll
        for (int r = 0; r < 16; ++r) {
            const int t = (r & 3) + 8 * (r >> 2) + 4 * hi;
            const float v = (t < 20) ? sacc[r] * SCALEF : -1e30f;
            pv[r] = v;
            vmax = fmaxf(vmax, v);
        }
        vmax = fmaxf(vmax, __shfl_xor(vmax, 32, 64));
        float psum = 0.f;
#pragma unroll
        for (int r = 0; r < 16; ++r) {
            const int t = (r & 3) + 8 * (r >> 2) + 4 * hi;
            const float e = (t < 20) ? __expf(pv[r] - vmax) : 0.f;
            pv[r] = e;
            psum += e;
        }
        psum += __shfl_xor(psum, 32, 64);
        const float inv = 1.f / psum;
        ushort* Pl = Qc;     // alias
        if (l31 < 20) {
            ushort* prow = Pl + (i20 + l31) * QS;
#pragma unroll
            for (int r = 0; r < 16; ++r) {
                const int t = (r & 3) + 8 * (r >> 2) + 4 * hi;
                if (t < 20) prow[t] = f2bf(pv[r] * inv);
            }
        }
        asm volatile("s_waitcnt lgkmcnt(0)" ::: "memory");
        __builtin_amdgcn_sched_barrier(0);

        // ---- PV: O[s][v]; Pl K-cols >=20 garbage killed by XVT zero cols ----
        unsigned plo0, phi0, plo1, phi1;
        {
            const int r1 = i20 + 16 + ((l15 < 4) ? l15 : 0);   // clamped (<40)
            const bf16x8 A0 = *(const bf16x8*)(Pl + (i20 + l15) * QS + lhi * 8);
            const bf16x8 B0 = *(const bf16x8*)(XVT + l15 * XV8 + item * 32 + lhi * 8);
            const f32x4 d0 = MFMA16(A0, B0, z4);
            const bf16x8 A1 = *(const bf16x8*)(Pl + r1 * QS + lhi * 8);
            const f32x4 d1 = MFMA16(A1, B0, z4);
            plo0 = ((unsigned)f2bf(d0[1]) << 16) | (unsigned)f2bf(d0[0]);
            phi0 = ((unsigned)f2bf(d0[3]) << 16) | (unsigned)f2bf(d0[2]);
            plo1 = ((unsigned)f2bf(d1[1]) << 16) | (unsigned)f2bf(d1[0]);
            phi1 = ((unsigned)f2bf(d1[3]) << 16) | (unsigned)f2bf(d1[2]);
        }
#define PV_CASE(H) case H: va##H = plo0; vb##H = phi0; vc##H = plo1; vd##H = phi1; break;
        switch (h) {
            PV_CASE(0) PV_CASE(1) PV_CASE(2) PV_CASE(3)
            PV_CASE(4) PV_CASE(5) PV_CASE(6) PV_CASE(7)
            PV_CASE(8) PV_CASE(9) PV_CASE(10) PV_CASE(11)
            PV_CASE(12) PV_CASE(13) PV_CASE(14) PV_CASE(15)
        }
#undef PV_CASE
        __syncthreads();   // head end: Qc/Pl + XVT safe to overwrite
    }

    // ---- unpack Vl -> LDS (alias Xbf) ----
    ushort* Vlbf = Xbf;
    __syncthreads();
#pragma unroll 1
    for (int h2 = 0; h2 < 16; ++h2) {
        unsigned a = 0, b2 = 0, c = 0, d = 0;
#define UNP_CASE(H) case H: a = va##H; b2 = vb##H; c = vc##H; d = vd##H; break;
        switch (h2) {
            UNP_CASE(0) UNP_CASE(1) UNP_CASE(2) UNP_CASE(3)
            UNP_CASE(4) UNP_CASE(5) UNP_CASE(6) UNP_CASE(7)
            UNP_CASE(8) UNP_CASE(9) UNP_CASE(10) UNP_CASE(11)
            UNP_CASE(12) UNP_CASE(13) UNP_CASE(14) UNP_CASE(15)
        }
#undef UNP_CASE
        ushort* base0 = Vlbf + (i20 + lhi * 4) * VS + h2 * 16 + l15;
        base0[0 * VS] = (ushort)(a & 0xffffu);
        base0[1 * VS] = (ushort)(a >> 16);
        base0[2 * VS] = (ushort)(b2 & 0xffffu);
        base0[3 * VS] = (ushort)(b2 >> 16);
        if (lhi == 0) {
            ushort* base1 = Vlbf + (i20 + 16) * VS + h2 * 16 + l15;
            base1[0 * VS] = (ushort)(c & 0xffffu);
            base1[1 * VS] = (ushort)(c >> 16);
            base1[2 * VS] = (ushort)(d & 0xffffu);
            base1[3 * VS] = (ushort)(d >> 16);
        }
    }
    __syncthreads();

    // ---- keys GEMM + tanh + qv-dot (39 tiles over 2 waves) ----
    for (int tile = w; tile < 39; tile += 2) {
        const int m = tile / 13, n = tile - m * 13;
        const int q = 16 * n + l15;
        const float bkq = (q < QDIM) ? bk[q] : 0.f;
        const float qvq = (q < QDIM) ? qv[q] : 0.f;
        int arow = 16 * m + l15;
        if (arow >= 40) arow -= 8;      // clamp garbage lanes in-range
        f32x4 acc = z4;
#pragma unroll
        for (int ks = 0; ks < 8; ++ks) {
            const int off = ks * 32 + lhi * 8;
            const bf16x8 A = *(const bf16x8*)(Vlbf + arow * VS + off);
            const bf16x8 B = *(const bf16x8*)(WkT + (16 * n + l15) * 256 + off);
            acc = MFMA16(A, B, acc);
        }
#pragma unroll
        for (int r = 0; r < 4; ++r) {
            float c = qvq * tanhf(acc[r] + bkq);
            c += __shfl_xor(c, 1, 64);
            c += __shfl_xor(c, 2, 64);
            c += __shfl_xor(c, 4, 64);
            c += __shfl_xor(c, 8, 64);
            const int srow = 16 * m + lhi * 4 + r;
            if (l15 == 0 && srow < 40) atomicAdd(&wrf[srow], c);
        }
    }
    __syncthreads();

    if (tid < 2) {
        const int i = tid;
        float m = -1e30f;
        for (int s = 0; s < 20; ++s) m = fmaxf(m, wrf[20 * i + s] * SCALEF);
        float sum = 0.f;
        for (int s = 0; s < 20; ++s) {
            const float e = __expf(wrf[20 * i + s] * SCALEF - m);
            wrf[20 * i + s] = e; sum += e;
        }
        const float invs = 1.f / sum;
        for (int s = 0; s < 20; ++s) wrf[20 * i + s] *= invs;
    }
    __syncthreads();

    for (int idx = tid; idx < 2 * 256; idx += 128) {
        const int i = idx >> 8, r = idx & 255;
        float s = 0.f;
#pragma unroll
        for (int t = 0; t < 20; ++t)
            s += wrf[20 * i + t] * bf2f(Vlbf[(20 * i + t) * VS + r]);
        const int gi = blockIdx.x * 2 + i;
        const int b = gi / NITEMS, it = gi - b * NITEMS;
        float* op = (it < CDD) ? (cddR + (b * CDD + it) * RP)
                               : (hisR + (b * HIS + (it - CDD)) * RP);
        op[r] = s;
    }
}

// ---------------------------------------------------------------------------
// Word encoder v6 (fallback when EV table unavailable) — unchanged
// ---------------------------------------------------------------------------
__device__ __forceinline__ void qc_et(const ushort* __restrict__ WqAh,
                                      const ushort* Xl, ushort* Qcl,
                                      int et, int jcol, int l31, int hi)
{
    f32x16 acc0 = zero16(), acc1 = zero16(), acc2 = zero16(),
           acc3 = zero16(), acc4 = zero16();
    const ushort* abase = WqAh + (et * 20) * 512 + l31 * 16 + hi * 8;
    bf16x8 Abuf[5];
#pragma unroll
    for (int i = 0; i < 5; ++i) Abuf[i] = *(const bf16x8*)(abase + i * 512);
    __builtin_amdgcn_s_setprio(1);
#pragma unroll
    for (int ks = 0; ks < 20; ++ks) {
        const bf16x8 A = Abuf[ks % 5];
        const int xoff = ks * 16 + hi * 8;
        const bf16x8 B0 = *(const bf16x8*)(Xl + (0 * 32 + l31) * XS + xoff);
        acc0 = MFMA32(A, B0, acc0);
        const bf16x8 B1 = *(const bf16x8*)(Xl + (1 * 32 + l31) * XS + xoff);
        acc1 = MFMA32(A, B1, acc1);
        const bf16x8 B2 = *(const bf16x8*)(Xl + (2 * 32 + l31) * XS + xoff);
        acc2 = MFMA32(A, B2, acc2);
        const bf16x8 B3 = *(const bf16x8*)(Xl + (3 * 32 + l31) * XS + xoff);
        acc3 = MFMA32(A, B3, acc3);
        const bf16x8 B4 = *(const bf16x8*)(Xl + (4 * 32 + l31) * XS + xoff);
        acc4 = MFMA32(A, B4, acc4);
        if (ks + 5 < 20) Abuf[ks % 5] = *(const bf16x8*)(abase + (ks + 5) * 512);
    }
    __builtin_amdgcn_s_setprio(0);
#pragma unroll
    for (int m = 0; m < 5; ++m) {
        f32x16 a;
        switch (m) {
            case 0: a = acc0; break; case 1: a = acc1; break;
            case 2: a = acc2; break; case 3: a = acc3; break;
            default: a = acc4; break;
        }
        ushort* qrow = Qcl + (32 * m + l31) * QS + jcol * 32;
#pragma unroll
        for (int g = 0; g < 4; ++g) {
            short4v p;
            p.x = (short)f2bf(a[4 * g + 0]);
            p.y = (short)f2bf(a[4 * g + 1]);
            p.z = (short)f2bf(a[4 * g + 2]);
            p.w = (short)f2bf(a[4 * g + 3]);
            *(short4v*)(qrow + 8 * g + 4 * hi) = p;
        }
    }
}

template<int NT>
__device__ __forceinline__ void s_chunk(const ushort* Xl, const ushort* Qcl,
                                        f32x16& sacc, int ebase, int i20,
                                        int l31, int hi)
{
    const ushort* xr = Xl + (i20 + l31) * XS + ebase + hi * 8;
    const ushort* qr = Qcl + (i20 + l31) * QS + hi * 8;
#pragma unroll
    for (int kst = 0; kst < 2 * NT; ++kst) {
        const bf16x8 A = *(const bf16x8*)(xr + kst * 16);
        const bf16x8 B = *(const bf16x8*)(qr + kst * 16);
        sacc = MFMA32(A, B, sacc);
    }
}

__global__ __launch_bounds__(512, 2)
void word_encoder_mfma(const int* __restrict__ cddT, const int* __restrict__ hisT,
                       const float* __restrict__ E,
                       const ushort* __restrict__ WqA, const ushort* __restrict__ WvT,
                       const ushort* __restrict__ WkT,
                       const float* __restrict__ bk, const float* __restrict__ qv,
                       float* __restrict__ cddR, float* __restrict__ hisR)
{
    __shared__ ushort Xbf[160 * XS];
    __shared__ ushort Qc[160 * QS];
    __shared__ ushort XVT[16 * XVS];
    __shared__ ushort toks[160];
    __shared__ float  wrf[160];

    const int tid = threadIdx.x;
    const int w   = tid >> 6;
    const int l31 = tid & 31;
    const int hi  = (tid >> 5) & 1;
    const int l15 = tid & 15;
    const int lhi = (tid >> 4) & 3;
    const f32x4 z4 = {0.f, 0.f, 0.f, 0.f};

    for (int i = tid; i < (160 * XS) / 2; i += 512) ((unsigned*)Xbf)[i] = 0u;
    for (int i = tid; i < (16 * XVS) / 2; i += 512) ((unsigned*)XVT)[i] = 0u;
    if (tid < 160) {
        wrf[tid] = 0.f;
        const int it_l = tid / 20, t = tid - it_l * 20;
        const int gi = blockIdx.x * 8 + it_l;
        const int b = gi / NITEMS, it = gi - b * NITEMS;
        const int tk = (it < CDD) ? cddT[(b * CDD + it) * TT + t]
                                  : hisT[(b * HIS + (it - CDD)) * TT + t];
        toks[tid] = (ushort)tk;
    }
    __syncthreads();

    for (int idx = tid; idx < 160 * 38; idx += 512) {
        const int r = idx / 38, g = idx - r * 38;
        const long base = (long)toks[r] * 300 + g * 8;
        short4v p0, p1;
        if (g < 37) {
            const float4 v0 = *(const float4*)(E + base);
            const float4 v1 = *(const float4*)(E + base + 4);
            p0.x = (short)f2bf(v0.x); p0.y = (short)f2bf(v0.y);
            p0.z = (short)f2bf(v0.z); p0.w = (short)f2bf(v0.w);
            p1.x = (short)f2bf(v1.x); p1.y = (short)f2bf(v1.y);
            p1.z = (short)f2bf(v1.z); p1.w = (short)f2bf(v1.w);
        } else {
            const float4 v0 = *(const float4*)(E + base);
            p0.x = (short)f2bf(v0.x); p0.y = (short)f2bf(v0.y);
            p0.z = (short)f2bf(v0.z); p0.w = (short)f2bf(v0.w);
            p1.x = 0; p1.y = 0; p1.z = 0; p1.w = 0;
        }
        *(short4v*)(Xbf + r * XS + g * 8) = p0;
        *(short4v*)(Xbf + r * XS + g * 8 + 4) = p1;
    }
    __syncthreads();

    unsigned va0=0,va1=0,va2=0,va3=0,va4=0,va5=0,va6=0,va7=0;
    unsigned va8=0,va9=0,va10=0,va11=0,va12=0,va13=0,va14=0,va15=0;
    unsigned vb0=0,vb1=0,vb2=0,vb3=0,vb4=0,vb5=0,vb6=0,vb7=0;
    unsigned vb8=0,vb9=0,vb10=0,vb11=0,vb12=0,vb13=0,vb14=0,vb15=0;
    unsigned vc0=0,vc1=0,vc2=0,vc3=0,vc4=0,vc5=0,vc6=0,vc7=0;
    unsigned vc8=0,vc9=0,vc10=0,vc11=0,vc12=0,vc13=0,vc14=0,vc15=0;
    unsigned vd0=0,vd1=0,vd2=0,vd3=0,vd4=0,vd5=0,vd6=0,vd7=0;
    unsigned vd8=0,vd9=0,vd10=0,vd11=0,vd12=0,vd13=0,vd14=0,vd15=0;

    const int item = w;
    const int i20  = item * 20;

#pragma unroll 1
    for (int h = 0; h < 16; ++h) {
        const ushort* WqAh = WqA + h * 102400;
        f32x16 sacc = zero16();

        if (w < 4) {
            qc_et(WqAh, Xbf, Qc, w, w, l31, hi);
        } else {
            for (int tt = w - 4; tt < 10; tt += 4) {
                f32x4 acc = z4;
#pragma unroll
                for (int ks = 0; ks < 10; ++ks) {
                    const int off = ks * 32 + lhi * 8;
                    const bf16x8 A = *(const bf16x8*)(WvT + (h * 16 + l15) * 320 + off);
                    const bf16x8 B = *(const bf16x8*)(Xbf + (tt * 16 + l15) * XS + off);
                    acc = MFMA16(A, B, acc);
                }
                const int t = tt * 16 + l15;
                const int it2 = t / 20, lt = t - it2 * 20;
#pragma unroll
                for (int r = 0; r < 4; ++r)
                    XVT[(lhi * 4 + r) * XVS + it2 * 32 + lt] = f2bf(acc[r]);
            }
        }
        __syncthreads();
        s_chunk<4>(Xbf, Qc, sacc, 0, i20, l31, hi);
        __syncthreads();

        if (w < 4) qc_et(WqAh, Xbf, Qc, 4 + w, w, l31, hi);
        __syncthreads();
        s_chunk<4>(Xbf, Qc, sacc, 128, i20, l31, hi);
        __syncthreads();

        if (w == 0 || w == 2) qc_et(WqAh, Xbf, Qc, 8 + (w >> 1), (w >> 1), l31, hi);
        __syncthreads();
        s_chunk<2>(Xbf, Qc, sacc, 256, i20, l31, hi);
        __syncthreads();

        float sv[16];
        float vmax = -1e30f;
#pragma unroll
        for (int r = 0; r < 16; ++r) {
            const int t = (r & 3) + 8 * (r >> 2) + 4 * hi;
            const float v = (t < 20) ? sacc[r] * SCALEF : -1e30f;
            sv[r] = v;
            vmax = fmaxf(vmax, v);
        }
        vmax = fmaxf(vmax, __shfl_xor(vmax, 32, 64));
        float psum = 0.f;
        float pv[16];
#pragma unroll
        for (int r = 0; r < 16; ++r) {
            const int t = (r & 3) + 8 * (r >> 2) + 4 * hi;
            const float e = (t < 20) ? __expf(sv[r] - vmax) : 0.f;
            pv[r] = e;
            psum += e;
        }
        psum += __shfl_xor(psum, 32, 64);
        const float inv = 1.f / psum;
        ushort* Pl = Qc;
        if (l31 < 20) {
            ushort* prow = Pl + (i20 + l31) * QS;
#pragma unroll
            for (int r = 0; r < 16; ++r) {
                const int t = (r & 3) + 8 * (r >> 2) + 4 * hi;
                if (t < 20) prow[t] = f2bf(pv[r] * inv);
            }
        }
        asm volatile("s_waitcnt lgkmcnt(0)" ::: "memory");
        __builtin_amdgcn_sched_barrier(0);

        unsigned plo0, phi0, plo1, phi1;
        {
            const bf16x8 A0 = *(const bf16x8*)(Pl + (i20 + l15) * QS + lhi * 8);
            const bf16x8 B0 = *(const bf16x8*)(XVT + l15 * XVS + item * 32 + lhi * 8);
            const f32x4 d0 = MFMA16(A0, B0, z4);
            const bf16x8 A1 = *(const bf16x8*)(Pl + (i20 + 16 + l15) * QS + lhi * 8);
            const f32x4 d1 = MFMA16(A1, B0, z4);
            plo0 = ((unsigned)f2bf(d0[1]) << 16) | (unsigned)f2bf(d0[0]);
            phi0 = ((unsigned)f2bf(d0[3]) << 16) | (unsigned)f2bf(d0[2]);
            plo1 = ((unsigned)f2bf(d1[1]) << 16) | (unsigned)f2bf(d1[0]);
            phi1 = ((unsigned)f2bf(d1[3]) << 16) | (unsigned)f2bf(d1[2]);
        }
#define PV_CASE(H) case H: va##H = plo0; vb##H = phi0; vc##H = plo1; vd##H = phi1; break;
        switch (h) {
            PV_CASE(0) PV_CASE(1) PV_CASE(2) PV_CASE(3)
            PV_CASE(4) PV_CASE(5) PV_CASE(6) PV_CASE(7)
            PV_CASE(8) PV_CASE(9) PV_CASE(10) PV_CASE(11)
            PV_CASE(12) PV_CASE(13) PV_CASE(14) PV_CASE(15)
        }
#undef PV_CASE
        __syncthreads();
    }

    ushort* Vlbf = Xbf;
    __syncthreads();
#pragma unroll 1
    for (int h2 = 0; h2 < 16; ++h2) {
        unsigned a = 0, b2 = 0, c = 0, d = 0;
#define UNP_CASE(H) case H: a = va##H; b2 = vb##H; c = vc##H; d = vd##H; break;
        switch (h2) {
            UNP_CASE(0) UNP_CASE(1) UNP_CASE(2) UNP_CASE(3)
            UNP_CASE(4) UNP_CASE(5) UNP_CASE(6) UNP_CASE(7)
            UNP_CASE(8) UNP_CASE(9) UNP_CASE(10) UNP_CASE(11)
            UNP_CASE(12) UNP_CASE(13) UNP_CASE(14) UNP_CASE(15)
        }
#undef UNP_CASE
        ushort* base0 = Vlbf + (i20 + lhi * 4) * VS + h2 * 16 + l15;
        base0[0 * VS] = (ushort)(a & 0xffffu);
        base0[1 * VS] = (ushort)(a >> 16);
        base0[2 * VS] = (ushort)(b2 & 0xffffu);
        base0[3 * VS] = (ushort)(b2 >> 16);
        if (lhi == 0) {
            ushort* base1 = Vlbf + (i20 + 16) * VS + h2 * 16 + l15;
            base1[0 * VS] = (ushort)(c & 0xffffu);
            base1[1 * VS] = (ushort)(c >> 16);
            base1[2 * VS] = (ushort)(d & 0xffffu);
            base1[3 * VS] = (ushort)(d >> 16);
        }
    }
    __syncthreads();

    for (int tile = w; tile < 130; tile += 8) {
        const int m = tile / 13, n = tile - m * 13;
        const int q = 16 * n + l15;
        const float bkq = (q < QDIM) ? bk[q] : 0.f;
        const float qvq = (q < QDIM) ? qv[q] : 0.f;
        f32x4 acc = z4;
#pragma unroll
        for (int ks = 0; ks < 8; ++ks) {
            const int off = ks * 32 + lhi * 8;
            const bf16x8 A = *(const bf16x8*)(Vlbf + (16 * m + l15) * VS + off);
            const bf16x8 B = *(const bf16x8*)(WkT + (16 * n + l15) * 256 + off);
            acc = MFMA16(A, B, acc);
        }
#pragma unroll
        for (int r = 0; r < 4; ++r) {
            float c = qvq * tanhf(acc[r] + bkq);
            c += __shfl_xor(c, 1, 64);
            c += __shfl_xor(c, 2, 64);
            c += __shfl_xor(c, 4, 64);
            c += __shfl_xor(c, 8, 64);
            if (l15 == 0) atomicAdd(&wrf[16 * m + lhi * 4 + r], c);
        }
    }
    __syncthreads();

    if (tid < 8) {
        const int i = tid;
        float m = -1e30f;
        for (int s = 0; s < 20; ++s) m = fmaxf(m, wrf[20 * i + s] * SCALEF);
        float sum = 0.f;
        for (int s = 0; s < 20; ++s) {
            const float e = __expf(wrf[20 * i + s] * SCALEF - m);
            wrf[20 * i + s] = e; sum += e;
        }
        const float invs = 1.f / sum;
        for (int s = 0; s < 20; ++s) wrf[20 * i + s] *= invs;
    }
    __syncthreads();

    for (int idx = tid; idx < 8 * 256; idx += 512) {
        const int i = idx >> 8, r = idx & 255;
        float s = 0.f;
#pragma unroll
        for (int t = 0; t < 20; ++t)
            s += wrf[20 * i + t] * bf2f(Vlbf[(20 * i + t) * VS + r]);
        const int gi = blockIdx.x * 8 + i;
        const int b = gi / NITEMS, it = gi - b * NITEMS;
        float* op = (it < CDD) ? (cddR + (b * CDD + it) * RP)
                               : (hisR + (b * HIS + (it - CDD)) * RP);
        op[r] = s;
    }
}

// ---------------------------------------------------------------------------
// User encoder (MFMA) — unchanged
// ---------------------------------------------------------------------------
#define US   264
#define UTS  72
#define UXVS 72
#define UVS  264

__global__ __launch_bounds__(512, 2)
void user_encoder_mfma(const float* __restrict__ hisR,
                       const ushort* __restrict__ WqnT, const ushort* __restrict__ WvnT,
                       const ushort* __restrict__ WknT,
                       const float* __restrict__ bk, const float* __restrict__ qv,
                       float* __restrict__ userR)
{
    __shared__ ushort Xu[64 * US];
    __shared__ ushort Qu[64 * US];
    __shared__ ushort XVTu[16 * UXVS];
    __shared__ ushort Atu[64 * UTS];
    __shared__ ushort Vlu[64 * UVS];
    __shared__ float  wru[64];

    const int tid = threadIdx.x;
    const int w   = tid >> 6;
    const int l15 = tid & 15;
    const int lhi = (tid >> 4) & 3;
    const f32x4 z4 = {0.f, 0.f, 0.f, 0.f};

    for (int i = tid; i < (64 * US) / 2; i += 512) ((unsigned*)Xu)[i] = 0u;
    for (int i = tid; i < (64 * UTS) / 2; i += 512) ((unsigned*)Atu)[i] = 0u;
    for (int i = tid; i < (64 * UVS) / 2; i += 512) ((unsigned*)Vlu)[i] = 0u;
    if (tid < 64) wru[tid] = 0.f;
    __syncthreads();

    const float* xp = hisR + (long)blockIdx.x * (HIS * RP);
    for (int idx = tid; idx < 50 * 64; idx += 512) {
        const int s = idx >> 6, q = idx & 63;
        const float4 v = ((const float4*)xp)[idx];
        short4v p;
        p.x = (short)f2bf(v.x); p.y = (short)f2bf(v.y);
        p.z = (short)f2bf(v.z); p.w = (short)f2bf(v.w);
        *(short4v*)(Xu + s * US + q * 4) = p;
    }
    __syncthreads();

#pragma unroll 1
    for (int h = 0; h < 16; ++h) {
        const ushort* Wqh = WqnT + h * 65536;
        for (int t8 = w; t8 < 64; t8 += 8) {
            const int et = t8 >> 2, st = t8 & 3;
            f32x4 acc = z4;
#pragma unroll
            for (int ks = 0; ks < 8; ++ks) {
                const int off = ks * 32 + lhi * 8;
                const bf16x8 A = *(const bf16x8*)(Wqh + (16 * et + l15) * 256 + off);
                const bf16x8 B = *(const bf16x8*)(Xu + (16 * st + l15) * US + off);
                acc = MFMA16(A, B, acc);
            }
            short4v p;
            p.x = (short)f2bf(acc[0]); p.y = (short)f2bf(acc[1]);
            p.z = (short)f2bf(acc[2]); p.w = (short)f2bf(acc[3]);
            *(short4v*)(Qu + (16 * st + l15) * US + 16 * et + lhi * 4) = p;
        }
        __syncthreads();

        if (w < 4) {
            f32x4 a[4] = {z4, z4, z4, z4};
#pragma unroll
            for (int ks = 0; ks < 8; ++ks) {
                const int off = ks * 32 + lhi * 8;
                const bf16x8 qa = *(const bf16x8*)(Qu + (16 * w + l15) * US + off);
#pragma unroll
                for (int n = 0; n < 4; ++n)
                    a[n] = MFMA16(qa, *(const bf16x8*)(Xu + (16 * n + l15) * US + off), a[n]);
            }
#pragma unroll
            for (int r = 0; r < 4; ++r) {
                const int srow = 16 * w + lhi * 4 + r;
                float v[4];
                float m = -1e30f;
#pragma unroll
                for (int n = 0; n < 4; ++n) {
                    const int t = 16 * n + l15;
                    v[n] = (t < HIS) ? a[n][r] * SCALEF : -1e30f;
                    m = fmaxf(m, v[n]);
                }
                m = fmaxf(m, __shfl_xor(m, 1, 64));
                m = fmaxf(m, __shfl_xor(m, 2, 64));
                m = fmaxf(m, __shfl_xor(m, 4, 64));
                m = fmaxf(m, __shfl_xor(m, 8, 64));
                float p[4]; float sum = 0.f;
#pragma unroll
                for (int n = 0; n < 4; ++n) {
                    const int t = 16 * n + l15;
                    p[n] = (t < HIS) ? __expf(v[n] - m) : 0.f;
                    sum += p[n];
                }
                sum += __shfl_xor(sum, 1, 64);
                sum += __shfl_xor(sum, 2, 64);
                sum += __shfl_xor(sum, 4, 64);
                sum += __shfl_xor(sum, 8, 64);
                const float inv = 1.f / sum;
                if (srow < HIS) {
#pragma unroll
                    for (int n = 0; n < 4; ++n)
                        Atu[srow * UTS + 16 * n + l15] = f2bf(p[n] * inv);
                }
            }
        } else {
            const int j = w - 4;
            f32x4 acc = z4;
#pragma unroll
            for (int ks = 0; ks < 8; ++ks) {
                const int off = ks * 32 + lhi * 8;
                const bf16x8 A = *(const bf16x8*)(Xu + (16 * j + l15) * US + off);
                const bf16x8 B = *(const bf16x8*)(WvnT + (h * 16 + l15) * 256 + off);
                acc = MFMA16(A, B, acc);
            }
#pragma unroll
            for (int r = 0; r < 4; ++r)
                XVTu[l15 * UXVS + 16 * j + lhi * 4 + r] = f2bf(acc[r]);
        }
        __syncthreads();

        if (w < 4) {
            f32x4 acc = z4;
#pragma unroll
            for (int ks = 0; ks < 2; ++ks) {
                const int off = ks * 32 + lhi * 8;
                const bf16x8 A = *(const bf16x8*)(Atu + (16 * w + l15) * UTS + off);
                const bf16x8 B = *(const bf16x8*)(XVTu + l15 * UXVS + off);
                acc = MFMA16(A, B, acc);
            }
#pragma unroll
            for (int r = 0; r < 4; ++r) {
                const int srow = 16 * w + lhi * 4 + r;
                if (srow < HIS) Vlu[srow * UVS + h * 16 + l15] = f2bf(acc[r]);
            }
        }
        __syncthreads();
    }

    for (int tile = w; tile < 52; tile += 8) {
        const int m = tile / 13, n = tile - m * 13;
        const int q = 16 * n + l15;
        const float bkq = (q < QDIM) ? bk[q] : 0.f;
        const float qvq = (q < QDIM) ? qv[q] : 0.f;
        f32x4 acc = z4;
#pragma unroll
        for (int ks = 0; ks < 8; ++ks) {
            const int off = ks * 32 + lhi * 8;
            const bf16x8 A = *(const bf16x8*)(Vlu + (16 * m + l15) * UVS + off);
            const bf16x8 B = *(const bf16x8*)(WknT + (16 * n + l15) * 256 + off);
            acc = MFMA16(A, B, acc);
        }
#pragma unroll
        for (int r = 0; r < 4; ++r) {
            float c = qvq * tanhf(acc[r] + bkq);
            c += __shfl_xor(c, 1, 64);
            c += __shfl_xor(c, 2, 64);
            c += __shfl_xor(c, 4, 64);
            c += __shfl_xor(c, 8, 64);
            const int srow = 16 * m + lhi * 4 + r;
            if (l15 == 0 && srow < HIS) atomicAdd(&wru[srow], c);
        }
    }
    __syncthreads();
    if (tid == 0) {
        float m = -1e30f;
        for (int s = 0; s < HIS; ++s) m = fmaxf(m, wru[s] * SCALEF);
        float sum = 0.f;
        for (int s = 0; s < HIS; ++s) {
            const float e = __expf(wru[s] * SCALEF - m);
            wru[s] = e; sum += e;
        }
        const float inv = 1.f / sum;
        for (int s = 0; s < HIS; ++s) wru[s] *= inv;
    }
    __syncthreads();
    if (tid < 256) {
        float s = 0.f;
        for (int t = 0; t < HIS; ++t) s += wru[t] * bf2f(Vlu[t * UVS + tid]);
        userR[blockIdx.x * RP + tid] = s;
    }
}

// ---------------------------------------------------------------------------
// fp32 user encoder (fallback tier) — unchanged
// ---------------------------------------------------------------------------
#define FP2 257
#define CHW 129
__global__ __launch_bounds__(512)
void user_encoder_fp32(const float* __restrict__ hisR,
                       const float* __restrict__ Wq, const float* __restrict__ Wv,
                       const float* __restrict__ Wk, const float* __restrict__ bk,
                       const float* __restrict__ qv,
                       float* __restrict__ userR)
{
    __shared__ float Xs[HIS + 1][FP2];
    __shared__ float Vl[HIS][FP2];
    __shared__ float Qcf[HIS + 1][CHW];
    __shared__ float Sm[HIS][HIS + 2];
    __shared__ float XVh[HIS][VDIM + 1];
    __shared__ float wr[HIS];

    const int tid = threadIdx.x;
    const int b = blockIdx.x;
    const float* xp = hisR + b * (HIS * RP);
    for (int i = tid; i < HIS * RP; i += 512) {
        const int s = i >> 8, f = i & 255;
        Xs[s][f] = xp[i];
    }
    __syncthreads();
    for (int h = 0; h < NH; ++h) {
        for (int chunk = 0; chunk < 2; ++chunk) {
            __syncthreads();
            const int e0 = chunk * 128;
            {
                const int sg = tid >> 7, et = tid & 127;
                const int s0 = sg * 13 - (sg == 3 ? 1 : 0);
                const float* wq = Wq + h * (RP * RP) + e0 + et;
                float acc[13] = {};
                for (int f = 0; f < RP; ++f) {
                    const float w = wq[f * RP];
#pragma unroll
                    for (int i = 0; i < 13; ++i) acc[i] += Xs[s0 + i][f] * w;
                }
#pragma unroll
                for (int i = 0; i < 13; ++i) Qcf[s0 + i][et] = acc[i];
            }
            __syncthreads();
            for (int o = tid; o < HIS * HIS; o += 512) {
                const int s = o / HIS, t = o - s * HIS;
                float acc = (chunk == 0) ? 0.f : Sm[s][t];
                for (int e = 0; e < 128; ++e) acc += Qcf[s][e] * Xs[t][e0 + e];
                Sm[s][t] = acc;
            }
        }
        __syncthreads();
        if (tid < HIS) {
            const int s = tid;
            float m = -1e30f;
            for (int t = 0; t < HIS; ++t) m = fmaxf(m, Sm[s][t]);
            m *= SCALEF;
            float sum = 0.f;
            for (int t = 0; t < HIS; ++t) { const float e = __expf(Sm[s][t] * SCALEF - m); Sm[s][t] = e; sum += e; }
            const float inv = 1.f / sum;
            for (int t = 0; t < HIS; ++t) Sm[s][t] *= inv;
        }
        for (int o = tid; o < HIS * VDIM; o += 512) {
            const int t = o >> 4, v = o & 15;
            const float* wp = Wv + h * (RP * VDIM) + v;
            float acc = 0.f;
            for (int f = 0; f < RP; ++f) acc += Xs[t][f] * wp[f * VDIM];
            XVh[t][v] = acc;
        }
        __syncthreads();
        for (int o = tid; o < HIS * VDIM; o += 512) {
            const int s = o >> 4, v = o & 15;
            float acc = 0.f;
            for (int t = 0; t < HIS; ++t) acc += Sm[s][t] * XVh[t][v];
            Vl[s][h * VDIM + v] = acc;
        }
    }
    __syncthreads();
    {
        const int s = tid >> 3, g = tid & 7;
        float part = 0.f;
        if (s < HIS) {
            for (int q = g; q < QDIM; q += 8) {
                float acc = bk[q];
                const float* wp = Wk + q;
                for (int r = 0; r < RP; ++r) acc += Vl[s][r] * wp[r * QDIM];
                part += qv[q] * tanhf(acc);
            }
        }
        part += __shfl_down(part, 1, 64);
        part += __shfl_down(part, 2, 64);
        part += __shfl_down(part, 4, 64);
        if (g == 0 && s < HIS) wr[s] = part * SCALEF;
    }
    __syncthreads();
    if (tid == 0) {
        float m = -1e30f;
        for (int s = 0; s < HIS; ++s) m = fmaxf(m, wr[s]);
        float sum = 0.f;
        for (int s = 0; s < HIS; ++s) { const float e = __expf(wr[s] - m); wr[s] = e; sum += e; }
        const float inv = 1.f / sum;
        for (int s = 0; s < HIS; ++s) wr[s] *= inv;
    }
    __syncthreads();
    float* up = userR + b * RP;
    for (int r = tid; r < RP; r += 512) {
        float acc = 0.f;
        for (int s = 0; s < HIS; ++s) acc += wr[s] * Vl[s][r];
        up[r] = acc;
    }
}

// ---------------------------------------------------------------------------
// Scores: dot + log_softmax
// ---------------------------------------------------------------------------
__global__ __launch_bounds__(64)
void score_kernel(const float* __restrict__ cddR, const float* __restrict__ userR,
                  float* __restrict__ out)
{
    const int b = blockIdx.x;
    const int lane = threadIdx.x;
    const float* u = userR + b * RP;
    float sc[CDD];
#pragma unroll
    for (int c = 0; c < CDD; ++c) {
        const float* cr = cddR + (b * CDD + c) * RP;
        float part = 0.f;
        for (int r = lane; r < RP; r += 64) part += cr[r] * u[r];
#pragma unroll
        for (int off = 32; off > 0; off >>= 1) part += __shfl_down(part, off, 64);
        sc[c] = part;
    }
    if (lane == 0) {
        float m = -1e30f;
#pragma unroll
        for (int c = 0; c < CDD; ++c) m = fmaxf(m, sc[c]);
        float sum = 0.f;
#pragma unroll
        for (int c = 0; c < CDD; ++c) sum += __expf(sc[c] - m);
        const float lse = m + logf(sum);
#pragma unroll
        for (int c = 0; c < CDD; ++c) out[b * CDD + c] = sc[c] - lse;
    }
}

extern "C" void kernel_launch(void* const* d_in, const int* in_sizes, int n_in,
                              void* d_out, int out_size, void* d_ws, size_t ws_size,
                              hipStream_t stream) {
    const int*   cddT = (const int*)d_in[0];
    const int*   hisT = (const int*)d_in[1];
    const float* E    = (const float*)d_in[2];
    const float* Wq_w = (const float*)d_in[3];
    const float* Wv_w = (const float*)d_in[4];
    const float* Wk_w = (const float*)d_in[5];
    const float* bk_w = (const float*)d_in[6];
    const float* q_w  = (const float*)d_in[7];
    const float* Wq_n = (const float*)d_in[8];
    const float* Wv_n = (const float*)d_in[9];
    const float* Wk_n = (const float*)d_in[10];
    const float* bk_n = (const float*)d_in[11];
    const float* q_n  = (const float*)d_in[12];
    float* out = (float*)d_out;

    char* wsb = (char*)d_ws;
    float*  cdd_reprs = (float*)(wsb + 0);          //  1,310,720
    float*  his_reprs = (float*)(wsb + 1310720);    // 13,107,200
    float*  user_repr = (float*)(wsb + 14417920);   //    262,144
    ushort* WqA  = (ushort*)(wsb + 14680064);       //  3,276,800
    ushort* WvT  = (ushort*)(wsb + 17956864);       //    163,840
    ushort* WkT  = (ushort*)(wsb + 18120704);       //    106,496
    ushort* WqnT = (ushort*)(wsb + 18227200);       //  2,097,152
    ushort* WvnT = (ushort*)(wsb + 20324352);       //    131,072
    ushort* WknT = (ushort*)(wsb + 20455424);       //    106,496
    ushort* EV   = (ushort*)(wsb + 20561920);       // 25,600,000 -> 46,161,920
    const bool mid  = ws_size >= 20561920ULL + 2335232ULL;
    const bool big  = ws_size >= 46161920ULL;

    prep_wqa<<<dim3(2048), 256, 0, stream>>>(Wq_w, WqA);
    transpose_pad<<<dim3(10, 1, 16), 256, 0, stream>>>(Wv_w, WvT, 300, 16, 16, 320, 16, 4800, 5120);
    transpose_pad<<<dim3(8, 7, 1), 256, 0, stream>>>(Wk_w, WkT, 256, 200, 200, 256, 208, 0, 0);
    if (mid) {
        transpose_pad<<<dim3(8, 8, 16), 256, 0, stream>>>(Wq_n, WqnT, 256, 256, 256, 256, 256, 65536, 65536);
        transpose_pad<<<dim3(8, 1, 16), 256, 0, stream>>>(Wv_n, WvnT, 256, 16, 16, 256, 16, 4096, 4096);
        transpose_pad<<<dim3(8, 7, 1), 256, 0, stream>>>(Wk_n, WknT, 256, 200, 200, 256, 208, 0, 0);
    }

    if (big) {
        prep_ev<<<dim3(782), 256, 0, stream>>>(E, WvT, EV);
        word_encoder_v8<<<dim3(NB * NITEMS / 2), dim3(128), 0, stream>>>(
            cddT, hisT, E, WqA, EV, WkT, bk_w, q_w, cdd_reprs, his_reprs);
    } else {
        word_encoder_mfma<<<dim3(NB * NITEMS / 8), dim3(512), 0, stream>>>(
            cddT, hisT, E, WqA, WvT, WkT, bk_w, q_w, cdd_reprs, his_reprs);
    }
    if (mid)
        user_encoder_mfma<<<dim3(NB), dim3(512), 0, stream>>>(
            his_reprs, WqnT, WvnT, WknT, bk_n, q_n, user_repr);
    else
        user_encoder_fp32<<<dim3(NB), dim3(512), 0, stream>>>(
            his_reprs, Wq_n, Wv_n, Wk_n, bk_n, q_n, user_repr);
    score_kernel<<<dim3(NB), dim3(64), 0, stream>>>(cdd_reprs, user_repr, out);
}

// Round 10
// 2126.543 us; speedup vs baseline: 1.2407x; 1.2407x over previous
//
#include <hip/hip_runtime.h>
#include <hip/hip_bf16.h>
#include <math.h>

#define NB 256
#define CDD 5
#define HIS 50
#define NITEMS 55
#define TT 20
#define DD 300
#define NH 16
#define VDIM 16
#define RP 256
#define QDIM 200
#define SCALEF 0.057735026918962584f   // 1/sqrt(300)

typedef __attribute__((ext_vector_type(8)))  short bf16x8;
typedef __attribute__((ext_vector_type(4)))  short short4v;
typedef __attribute__((ext_vector_type(4)))  float f32x4;
typedef __attribute__((ext_vector_type(16))) float f32x16;

#define MFMA16(a,b,c) __builtin_amdgcn_mfma_f32_16x16x32_bf16((a),(b),(c),0,0,0)
#define MFMA32(a,b,c) __builtin_amdgcn_mfma_f32_32x32x16_bf16((a),(b),(c),0,0,0)

__device__ __forceinline__ ushort f2bf(float f) {
    union { float f; unsigned u; } c; c.f = f;
    unsigned u = c.u;
    return (ushort)((u + 0x7fffu + ((u >> 16) & 1u)) >> 16);
}
__device__ __forceinline__ float bf2f(ushort h) {
    union { unsigned u; float f; } c; c.u = ((unsigned)h) << 16;
    return c.f;
}

// LDS strides (elements); all ==4 mod 32 dwords -> conflict-light column reads.
#define XS  328
#define QS  136
#define VS  264
#define XVS 264   // fallback kernel's XVT stride
#define XV7 136   // v7 XVT stride

// ---------------------------------------------------------------------------
// prep_wqa: Wq[h][f 300][e 300] -> A-fragment-tiled bf16
//   WqA[h][et 10][ks 20][e_in 32][k_in 16], zero-padded.
// ---------------------------------------------------------------------------
__global__ __launch_bounds__(256)
void prep_wqa(const float* __restrict__ Wq, ushort* __restrict__ WqA)
{
    const int TOT = 16 * 102400;
    for (int idx = blockIdx.x * 256 + threadIdx.x; idx < TOT; idx += gridDim.x * 256) {
        const int h  = idx / 102400;
        int r  = idx - h * 102400;
        const int et = r / 10240;  r -= et * 10240;
        const int ks = r / 512;    r -= ks * 512;
        const int ei = r >> 4, ki = r & 15;
        const int e = et * 32 + ei, f = ks * 16 + ki;
        const float v = (e < 300 && f < 300) ? Wq[(h * 300 + f) * 300 + e] : 0.f;
        WqA[idx] = f2bf(v);
    }
}

// ---------------------------------------------------------------------------
// transpose_pad: dst[slice][c][r] = src[slice][r][c], bf16, padded
// ---------------------------------------------------------------------------
__global__ __launch_bounds__(256)
void transpose_pad(const float* __restrict__ src, ushort* __restrict__ dst,
                   int R, int C, int src_ld, int Rp, int Cv,
                   long src_ss, long dst_ss)
{
    __shared__ float T[32][33];
    const int r0 = blockIdx.x * 32;
    const int c0 = blockIdx.y * 32;
    const float* s = src + blockIdx.z * src_ss;
    ushort* d = dst + blockIdx.z * dst_ss;
    const int i = threadIdx.x >> 3;
    const int j4 = (threadIdx.x & 7) * 4;
#pragma unroll
    for (int t = 0; t < 4; ++t) {
        const int r = r0 + i, c = c0 + j4 + t;
        T[i][j4 + t] = (r < R && c < C) ? s[(long)r * src_ld + c] : 0.f;
    }
    __syncthreads();
#pragma unroll
    for (int t = 0; t < 4; ++t) {
        const int orow = c0 + i;
        const int ocol = r0 + j4 + t;
        if (orow < Cv && ocol < Rp)
            d[(long)orow * Rp + ocol] = f2bf(T[j4 + t][i]);
    }
}

// ---------------------------------------------------------------------------
// EV = E * Wv (all vocab):  EV[v][256] bf16.  64 rows per block.
// ---------------------------------------------------------------------------
__global__ __launch_bounds__(256)
void prep_ev(const float* __restrict__ E, const ushort* __restrict__ WvT,
             ushort* __restrict__ EV)
{
    __shared__ ushort Ebf[64 * XS];
    const int tid = threadIdx.x;
    const int r0 = blockIdx.x * 64;
    for (int i = tid; i < (64 * XS) / 2; i += 256) ((unsigned*)Ebf)[i] = 0u;
    __syncthreads();
    for (int idx = tid; idx < 64 * 75; idx += 256) {
        const int row = idx / 75, q = idx - row * 75;
        const int vr = r0 + row;
        if (vr < 50000) {
            const float4 v = ((const float4*)E)[(long)vr * 75 + q];
            short4v p;
            p.x = (short)f2bf(v.x); p.y = (short)f2bf(v.y);
            p.z = (short)f2bf(v.z); p.w = (short)f2bf(v.w);
            *(short4v*)(Ebf + row * XS + q * 4) = p;
        }
    }
    __syncthreads();
    const int w = tid >> 6, l15 = tid & 15, lhi = (tid >> 4) & 3;
    const f32x4 z4 = {0.f, 0.f, 0.f, 0.f};
    for (int n = 0; n < 16; ++n) {
        f32x4 acc = z4;
#pragma unroll
        for (int ks = 0; ks < 10; ++ks) {
            const int off = ks * 32 + lhi * 8;
            const bf16x8 A = *(const bf16x8*)(Ebf + (16 * w + l15) * XS + off);
            const bf16x8 B = *(const bf16x8*)(WvT + (16 * n + l15) * 320 + off);
            acc = MFMA16(A, B, acc);
        }
#pragma unroll
        for (int r = 0; r < 4; ++r) {
            const int row = r0 + 16 * w + lhi * 4 + r;
            if (row < 50000) EV[(long)row * 256 + 16 * n + l15] = f2bf(acc[r]);
        }
    }
}

__device__ __forceinline__ f32x16 zero16() {
    f32x16 z;
#pragma unroll
    for (int i = 0; i < 16; ++i) z[i] = 0.f;
    return z;
}

// ---------------------------------------------------------------------------
// qc_et3: one wave, one 32-e tile, 3 m-tiles (96 rows; m=2 writes rows<80).
// ---------------------------------------------------------------------------
__device__ __forceinline__ void qc_et3(const ushort* __restrict__ WqAh,
                                       const ushort* Xl, ushort* Qcl,
                                       int et, int jcol, int l31, int hi)
{
    f32x16 acc0 = zero16(), acc1 = zero16(), acc2 = zero16();
    const ushort* abase = WqAh + (et * 20) * 512 + l31 * 16 + hi * 8;
    bf16x8 Abuf[5];
#pragma unroll
    for (int i = 0; i < 5; ++i) Abuf[i] = *(const bf16x8*)(abase + i * 512);
    __builtin_amdgcn_s_setprio(1);
#pragma unroll
    for (int ks = 0; ks < 20; ++ks) {
        const bf16x8 A = Abuf[ks % 5];
        const int xoff = ks * 16 + hi * 8;
        const bf16x8 B0 = *(const bf16x8*)(Xl + (0 * 32 + l31) * XS + xoff);
        acc0 = MFMA32(A, B0, acc0);
        const bf16x8 B1 = *(const bf16x8*)(Xl + (1 * 32 + l31) * XS + xoff);
        acc1 = MFMA32(A, B1, acc1);
        const bf16x8 B2 = *(const bf16x8*)(Xl + (2 * 32 + l31) * XS + xoff);
        acc2 = MFMA32(A, B2, acc2);
        if (ks + 5 < 20) Abuf[ks % 5] = *(const bf16x8*)(abase + (ks + 5) * 512);
    }
    __builtin_amdgcn_s_setprio(0);
#pragma unroll
    for (int m = 0; m < 3; ++m) {
        f32x16 a;
        switch (m) { case 0: a = acc0; break; case 1: a = acc1; break; default: a = acc2; break; }
        if (m == 2 && l31 >= 16) continue;   // rows >= 80 not stored
        ushort* qrow = Qcl + (32 * m + l31) * QS + jcol * 32;
#pragma unroll
        for (int g = 0; g < 4; ++g) {
            short4v p;
            p.x = (short)f2bf(a[4 * g + 0]);
            p.y = (short)f2bf(a[4 * g + 1]);
            p.z = (short)f2bf(a[4 * g + 2]);
            p.w = (short)f2bf(a[4 * g + 3]);
            *(short4v*)(qrow + 8 * g + 4 * hi) = p;
        }
    }
}

template<int NT>
__device__ __forceinline__ void s_chunk(const ushort* Xl, const ushort* Qcl,
                                        f32x16& sacc, int ebase, int i20,
                                        int l31, int hi)
{
    const ushort* xr = Xl + (i20 + l31) * XS + ebase + hi * 8;
    const ushort* qr = Qcl + (i20 + l31) * QS + hi * 8;
    __builtin_amdgcn_s_setprio(1);
#pragma unroll
    for (int kst = 0; kst < 2 * NT; ++kst) {
        const bf16x8 A = *(const bf16x8*)(xr + kst * 16);
        const bf16x8 B = *(const bf16x8*)(qr + kst * 16);
        sacc = MFMA32(A, B, sacc);
    }
    __builtin_amdgcn_s_setprio(0);
}

// ---------------------------------------------------------------------------
// Word encoder v7: 4 items/block, 256 threads (4 waves), 79.2 KB LDS
// -> 2 independent blocks/CU. Requires EV table.
// ---------------------------------------------------------------------------
#define POOLE 39296   // ushorts: Xbf 26240 | Qc 10880 | XVT 2176

__global__ __launch_bounds__(256, 2)
void word_encoder_v7(const int* __restrict__ cddT, const int* __restrict__ hisT,
                     const float* __restrict__ E,
                     const ushort* __restrict__ WqA, const ushort* __restrict__ EV,
                     const ushort* __restrict__ WkT,
                     const float* __restrict__ bk, const float* __restrict__ qv,
                     float* __restrict__ cddR, float* __restrict__ hisR)
{
    __shared__ ushort pool[POOLE];
    __shared__ float  wrf[80];
    __shared__ int    toks[80];
    ushort* Xbf = pool;            // 80 x XS   (garbage reads up to "row 95" stay in-pool)
    ushort* Qc  = pool + 26240;    // 80 x QS   (garbage reads up to "row 91" stay in-pool)
    ushort* XVT = pool + 37120;    // 16 x XV7  (cols t>=20 zero; never written)

    const int tid = threadIdx.x;
    const int w   = tid >> 6;
    const int l31 = tid & 31;
    const int hi  = (tid >> 5) & 1;
    const int l15 = tid & 15;
    const int lhi = (tid >> 4) & 3;
    const f32x4 z4 = {0.f, 0.f, 0.f, 0.f};
    const int item = w;
    const int i20  = item * 20;

    for (int i = tid; i < 26240 / 2; i += 256) ((unsigned*)Xbf)[i] = 0u;
    for (int i = tid; i < 2176 / 2; i += 256) ((unsigned*)XVT)[i] = 0u;
    if (tid < 80) {
        wrf[tid] = 0.f;
        const int it_l = tid / 20, t = tid - it_l * 20;
        const int gi = blockIdx.x * 4 + it_l;
        const int b = gi / NITEMS, it = gi - b * NITEMS;
        toks[tid] = (it < CDD) ? cddT[(b * CDD + it) * TT + t]
                               : hisT[(b * HIS + (it - CDD)) * TT + t];
    }
    __syncthreads();

    // ---- embeddings -> bf16 LDS (80 rows) ----
    for (int idx = tid; idx < 80 * 38; idx += 256) {
        const int r = idx / 38, g = idx - r * 38;
        const long base = (long)toks[r] * 300 + g * 8;
        short4v p0, p1;
        if (g < 37) {
            const float4 v0 = *(const float4*)(E + base);
            const float4 v1 = *(const float4*)(E + base + 4);
            p0.x = (short)f2bf(v0.x); p0.y = (short)f2bf(v0.y);
            p0.z = (short)f2bf(v0.z); p0.w = (short)f2bf(v0.w);
            p1.x = (short)f2bf(v1.x); p1.y = (short)f2bf(v1.y);
            p1.z = (short)f2bf(v1.z); p1.w = (short)f2bf(v1.w);
        } else {
            const float4 v0 = *(const float4*)(E + base);
            p0.x = (short)f2bf(v0.x); p0.y = (short)f2bf(v0.y);
            p0.z = (short)f2bf(v0.z); p0.w = (short)f2bf(v0.w);
            p1.x = 0; p1.y = 0; p1.z = 0; p1.w = 0;
        }
        *(short4v*)(Xbf + r * XS + g * 8) = p0;
        *(short4v*)(Xbf + r * XS + g * 8 + 4) = p1;
    }
    __syncthreads();

    // per-item Vl packed accumulators: 16 heads x 4 u32
    unsigned va0=0,va1=0,va2=0,va3=0,va4=0,va5=0,va6=0,va7=0;
    unsigned va8=0,va9=0,va10=0,va11=0,va12=0,va13=0,va14=0,va15=0;
    unsigned vb0=0,vb1=0,vb2=0,vb3=0,vb4=0,vb5=0,vb6=0,vb7=0;
    unsigned vb8=0,vb9=0,vb10=0,vb11=0,vb12=0,vb13=0,vb14=0,vb15=0;
    unsigned vc0=0,vc1=0,vc2=0,vc3=0,vc4=0,vc5=0,vc6=0,vc7=0;
    unsigned vc8=0,vc9=0,vc10=0,vc11=0,vc12=0,vc13=0,vc14=0,vc15=0;
    unsigned vd0=0,vd1=0,vd2=0,vd3=0,vd4=0,vd5=0,vd6=0,vd7=0;
    unsigned vd8=0,vd9=0,vd10=0,vd11=0,vd12=0,vd13=0,vd14=0,vd15=0;

#pragma unroll 1
    for (int h = 0; h < 16; ++h) {
        const ushort* WqAh = WqA + h * 102400;
        f32x16 sacc = zero16();

        // ---- P0: XVT fill (tid<160) + qc chunk0 (all waves) ----
        if (tid < 160) {
            const int tok = tid >> 1, half = tid & 1;
            const int it2 = tok / 20, lt = tok - it2 * 20;
            const ushort4* src = (const ushort4*)(EV + (long)toks[tok] * 256 + h * 16 + half * 8);
            const ushort4 a = src[0], b2 = src[1];
            ushort* dst0 = XVT + (half * 8) * XV7 + it2 * 32 + lt;
            dst0[0 * XV7] = a.x;  dst0[1 * XV7] = a.y;
            dst0[2 * XV7] = a.z;  dst0[3 * XV7] = a.w;
            dst0[4 * XV7] = b2.x; dst0[5 * XV7] = b2.y;
            dst0[6 * XV7] = b2.z; dst0[7 * XV7] = b2.w;
        }
        qc_et3(WqAh, Xbf, Qc, w, w, l31, hi);
        __syncthreads();
        s_chunk<4>(Xbf, Qc, sacc, 0, i20, l31, hi);
        __syncthreads();

        qc_et3(WqAh, Xbf, Qc, 4 + w, w, l31, hi);
        __syncthreads();
        s_chunk<4>(Xbf, Qc, sacc, 128, i20, l31, hi);
        __syncthreads();

        if ((w & 1) == 0) qc_et3(WqAh, Xbf, Qc, 8 + (w >> 1), (w >> 1), l31, hi);
        __syncthreads();
        s_chunk<2>(Xbf, Qc, sacc, 256, i20, l31, hi);
        __syncthreads();

        // ---- softmax over t per s=l31, in registers ----
        float pv[16];
        float vmax = -1e30f;
#pragma unroll
        for (int r = 0; r < 16; ++r) {
            const int t = (r & 3) + 8 * (r >> 2) + 4 * hi;
            const float v = (t < 20) ? sacc[r] * SCALEF : -1e30f;
            pv[r] = v;
            vmax = fmaxf(vmax, v);
        }
        vmax = fmaxf(vmax, __shfl_xor(vmax, 32, 64));
        float psum = 0.f;
#pragma unroll
        for (int r = 0; r < 16; ++r) {
            const int t = (r & 3) + 8 * (r >> 2) + 4 * hi;
            const float e = (t < 20) ? __expf(pv[r] - vmax) : 0.f;
            pv[r] = e;
            psum += e;
        }
        psum += __shfl_xor(psum, 32, 64);
        const float inv = 1.f / psum;
        ushort* Pl = Qc;     // alias
        if (l31 < 20) {
            ushort* prow = Pl + (i20 + l31) * QS;
#pragma unroll
            for (int r = 0; r < 16; ++r) {
                const int t = (r & 3) + 8 * (r >> 2) + 4 * hi;
                if (t < 20) prow[t] = f2bf(pv[r] * inv);
            }
        }
        asm volatile("s_waitcnt lgkmcnt(0)" ::: "memory");
        __builtin_amdgcn_sched_barrier(0);

        // ---- PV: O[s][v]; Pl K-cols >=20 garbage killed by XVT zero cols ----
        unsigned plo0, phi0, plo1, phi1;
        {
            const bf16x8 A0 = *(const bf16x8*)(Pl + (i20 + l15) * QS + lhi * 8);
            const bf16x8 B0 = *(const bf16x8*)(XVT + l15 * XV7 + item * 32 + lhi * 8);
            const f32x4 d0 = MFMA16(A0, B0, z4);
            const bf16x8 A1 = *(const bf16x8*)(Pl + (i20 + 16 + l15) * QS + lhi * 8);
            const f32x4 d1 = MFMA16(A1, B0, z4);
            plo0 = ((unsigned)f2bf(d0[1]) << 16) | (unsigned)f2bf(d0[0]);
            phi0 = ((unsigned)f2bf(d0[3]) << 16) | (unsigned)f2bf(d0[2]);
            plo1 = ((unsigned)f2bf(d1[1]) << 16) | (unsigned)f2bf(d1[0]);
            phi1 = ((unsigned)f2bf(d1[3]) << 16) | (unsigned)f2bf(d1[2]);
        }
#define PV_CASE(H) case H: va##H = plo0; vb##H = phi0; vc##H = plo1; vd##H = phi1; break;
        switch (h) {
            PV_CASE(0) PV_CASE(1) PV_CASE(2) PV_CASE(3)
            PV_CASE(4) PV_CASE(5) PV_CASE(6) PV_CASE(7)
            PV_CASE(8) PV_CASE(9) PV_CASE(10) PV_CASE(11)
            PV_CASE(12) PV_CASE(13) PV_CASE(14) PV_CASE(15)
        }
#undef PV_CASE
        __syncthreads();   // head end: Qc/Pl + XVT safe to overwrite
    }

    // ---- unpack Vl -> LDS (alias Xbf) ----
    ushort* Vlbf = Xbf;
    __syncthreads();
#pragma unroll 1
    for (int h2 = 0; h2 < 16; ++h2) {
        unsigned a = 0, b2 = 0, c = 0, d = 0;
#define UNP_CASE(H) case H: a = va##H; b2 = vb##H; c = vc##H; d = vd##H; break;
        switch (h2) {
            UNP_CASE(0) UNP_CASE(1) UNP_CASE(2) UNP_CASE(3)
            UNP_CASE(4) UNP_CASE(5) UNP_CASE(6) UNP_CASE(7)
            UNP_CASE(8) UNP_CASE(9) UNP_CASE(10) UNP_CASE(11)
            UNP_CASE(12) UNP_CASE(13) UNP_CASE(14) UNP_CASE(15)
        }
#undef UNP_CASE
        ushort* base0 = Vlbf + (i20 + lhi * 4) * VS + h2 * 16 + l15;
        base0[0 * VS] = (ushort)(a & 0xffffu);
        base0[1 * VS] = (ushort)(a >> 16);
        base0[2 * VS] = (ushort)(b2 & 0xffffu);
        base0[3 * VS] = (ushort)(b2 >> 16);
        if (lhi == 0) {
            ushort* base1 = Vlbf + (i20 + 16) * VS + h2 * 16 + l15;
            base1[0 * VS] = (ushort)(c & 0xffffu);
            base1[1 * VS] = (ushort)(c >> 16);
            base1[2 * VS] = (ushort)(d & 0xffffu);
            base1[3 * VS] = (ushort)(d >> 16);
        }
    }
    __syncthreads();

    // ---- keys GEMM + tanh + qv-dot ----
    for (int tile = w; tile < 65; tile += 4) {
        const int m = tile / 13, n = tile - m * 13;
        const int q = 16 * n + l15;
        const float bkq = (q < QDIM) ? bk[q] : 0.f;
        const float qvq = (q < QDIM) ? qv[q] : 0.f;
        f32x4 acc = z4;
#pragma unroll
        for (int ks = 0; ks < 8; ++ks) {
            const int off = ks * 32 + lhi * 8;
            const bf16x8 A = *(const bf16x8*)(Vlbf + (16 * m + l15) * VS + off);
            const bf16x8 B = *(const bf16x8*)(WkT + (16 * n + l15) * 256 + off);
            acc = MFMA16(A, B, acc);
        }
#pragma unroll
        for (int r = 0; r < 4; ++r) {
            float c = qvq * tanhf(acc[r] + bkq);
            c += __shfl_xor(c, 1, 64);
            c += __shfl_xor(c, 2, 64);
            c += __shfl_xor(c, 4, 64);
            c += __shfl_xor(c, 8, 64);
            if (l15 == 0) atomicAdd(&wrf[16 * m + lhi * 4 + r], c);
        }
    }
    __syncthreads();

    if (tid < 4) {
        const int i = tid;
        float m = -1e30f;
        for (int s = 0; s < 20; ++s) m = fmaxf(m, wrf[20 * i + s] * SCALEF);
        float sum = 0.f;
        for (int s = 0; s < 20; ++s) {
            const float e = __expf(wrf[20 * i + s] * SCALEF - m);
            wrf[20 * i + s] = e; sum += e;
        }
        const float invs = 1.f / sum;
        for (int s = 0; s < 20; ++s) wrf[20 * i + s] *= invs;
    }
    __syncthreads();

    for (int idx = tid; idx < 4 * 256; idx += 256) {
        const int i = idx >> 8, r = idx & 255;
        float s = 0.f;
#pragma unroll
        for (int t = 0; t < 20; ++t)
            s += wrf[20 * i + t] * bf2f(Vlbf[(20 * i + t) * VS + r]);
        const int gi = blockIdx.x * 4 + i;
        const int b = gi / NITEMS, it = gi - b * NITEMS;
        float* op = (it < CDD) ? (cddR + (b * CDD + it) * RP)
                               : (hisR + (b * HIS + (it - CDD)) * RP);
        op[r] = s;
    }
}

// ---------------------------------------------------------------------------
// Word encoder v6 (fallback when EV table unavailable) — unchanged
// ---------------------------------------------------------------------------
__device__ __forceinline__ void qc_et(const ushort* __restrict__ WqAh,
                                      const ushort* Xl, ushort* Qcl,
                                      int et, int jcol, int l31, int hi)
{
    f32x16 acc0 = zero16(), acc1 = zero16(), acc2 = zero16(),
           acc3 = zero16(), acc4 = zero16();
    const ushort* abase = WqAh + (et * 20) * 512 + l31 * 16 + hi * 8;
    bf16x8 Abuf[5];
#pragma unroll
    for (int i = 0; i < 5; ++i) Abuf[i] = *(const bf16x8*)(abase + i * 512);
    __builtin_amdgcn_s_setprio(1);
#pragma unroll
    for (int ks = 0; ks < 20; ++ks) {
        const bf16x8 A = Abuf[ks % 5];
        const int xoff = ks * 16 + hi * 8;
        const bf16x8 B0 = *(const bf16x8*)(Xl + (0 * 32 + l31) * XS + xoff);
        acc0 = MFMA32(A, B0, acc0);
        const bf16x8 B1 = *(const bf16x8*)(Xl + (1 * 32 + l31) * XS + xoff);
        acc1 = MFMA32(A, B1, acc1);
        const bf16x8 B2 = *(const bf16x8*)(Xl + (2 * 32 + l31) * XS + xoff);
        acc2 = MFMA32(A, B2, acc2);
        const bf16x8 B3 = *(const bf16x8*)(Xl + (3 * 32 + l31) * XS + xoff);
        acc3 = MFMA32(A, B3, acc3);
        const bf16x8 B4 = *(const bf16x8*)(Xl + (4 * 32 + l31) * XS + xoff);
        acc4 = MFMA32(A, B4, acc4);
        if (ks + 5 < 20) Abuf[ks % 5] = *(const bf16x8*)(abase + (ks + 5) * 512);
    }
    __builtin_amdgcn_s_setprio(0);
#pragma unroll
    for (int m = 0; m < 5; ++m) {
        f32x16 a;
        switch (m) {
            case 0: a = acc0; break; case 1: a = acc1; break;
            case 2: a = acc2; break; case 3: a = acc3; break;
            default: a = acc4; break;
        }
        ushort* qrow = Qcl + (32 * m + l31) * QS + jcol * 32;
#pragma unroll
        for (int g = 0; g < 4; ++g) {
            short4v p;
            p.x = (short)f2bf(a[4 * g + 0]);
            p.y = (short)f2bf(a[4 * g + 1]);
            p.z = (short)f2bf(a[4 * g + 2]);
            p.w = (short)f2bf(a[4 * g + 3]);
            *(short4v*)(qrow + 8 * g + 4 * hi) = p;
        }
    }
}

__global__ __launch_bounds__(512, 2)
void word_encoder_mfma(const int* __restrict__ cddT, const int* __restrict__ hisT,
                       const float* __restrict__ E,
                       const ushort* __restrict__ WqA, const ushort* __restrict__ WvT,
                       const ushort* __restrict__ WkT,
                       const float* __restrict__ bk, const float* __restrict__ qv,
                       float* __restrict__ cddR, float* __restrict__ hisR)
{
    __shared__ ushort Xbf[160 * XS];
    __shared__ ushort Qc[160 * QS];
    __shared__ ushort XVT[16 * XVS];
    __shared__ ushort toks[160];
    __shared__ float  wrf[160];

    const int tid = threadIdx.x;
    const int w   = tid >> 6;
    const int l31 = tid & 31;
    const int hi  = (tid >> 5) & 1;
    const int l15 = tid & 15;
    const int lhi = (tid >> 4) & 3;
    const f32x4 z4 = {0.f, 0.f, 0.f, 0.f};

    for (int i = tid; i < (160 * XS) / 2; i += 512) ((unsigned*)Xbf)[i] = 0u;
    for (int i = tid; i < (16 * XVS) / 2; i += 512) ((unsigned*)XVT)[i] = 0u;
    if (tid < 160) {
        wrf[tid] = 0.f;
        const int it_l = tid / 20, t = tid - it_l * 20;
        const int gi = blockIdx.x * 8 + it_l;
        const int b = gi / NITEMS, it = gi - b * NITEMS;
        const int tk = (it < CDD) ? cddT[(b * CDD + it) * TT + t]
                                  : hisT[(b * HIS + (it - CDD)) * TT + t];
        toks[tid] = (ushort)tk;
    }
    __syncthreads();

    for (int idx = tid; idx < 160 * 38; idx += 512) {
        const int r = idx / 38, g = idx - r * 38;
        const long base = (long)toks[r] * 300 + g * 8;
        short4v p0, p1;
        if (g < 37) {
            const float4 v0 = *(const float4*)(E + base);
            const float4 v1 = *(const float4*)(E + base + 4);
            p0.x = (short)f2bf(v0.x); p0.y = (short)f2bf(v0.y);
            p0.z = (short)f2bf(v0.z); p0.w = (short)f2bf(v0.w);
            p1.x = (short)f2bf(v1.x); p1.y = (short)f2bf(v1.y);
            p1.z = (short)f2bf(v1.z); p1.w = (short)f2bf(v1.w);
        } else {
            const float4 v0 = *(const float4*)(E + base);
            p0.x = (short)f2bf(v0.x); p0.y = (short)f2bf(v0.y);
            p0.z = (short)f2bf(v0.z); p0.w = (short)f2bf(v0.w);
            p1.x = 0; p1.y = 0; p1.z = 0; p1.w = 0;
        }
        *(short4v*)(Xbf + r * XS + g * 8) = p0;
        *(short4v*)(Xbf + r * XS + g * 8 + 4) = p1;
    }
    __syncthreads();

    unsigned va0=0,va1=0,va2=0,va3=0,va4=0,va5=0,va6=0,va7=0;
    unsigned va8=0,va9=0,va10=0,va11=0,va12=0,va13=0,va14=0,va15=0;
    unsigned vb0=0,vb1=0,vb2=0,vb3=0,vb4=0,vb5=0,vb6=0,vb7=0;
    unsigned vb8=0,vb9=0,vb10=0,vb11=0,vb12=0,vb13=0,vb14=0,vb15=0;
    unsigned vc0=0,vc1=0,vc2=0,vc3=0,vc4=0,vc5=0,vc6=0,vc7=0;
    unsigned vc8=0,vc9=0,vc10=0,vc11=0,vc12=0,vc13=0,vc14=0,vc15=0;
    unsigned vd0=0,vd1=0,vd2=0,vd3=0,vd4=0,vd5=0,vd6=0,vd7=0;
    unsigned vd8=0,vd9=0,vd10=0,vd11=0,vd12=0,vd13=0,vd14=0,vd15=0;

    const int item = w;
    const int i20  = item * 20;

#pragma unroll 1
    for (int h = 0; h < 16; ++h) {
        const ushort* WqAh = WqA + h * 102400;
        f32x16 sacc = zero16();

        if (w < 4) {
            qc_et(WqAh, Xbf, Qc, w, w, l31, hi);
        } else {
            for (int tt = w - 4; tt < 10; tt += 4) {
                f32x4 acc = z4;
#pragma unroll
                for (int ks = 0; ks < 10; ++ks) {
                    const int off = ks * 32 + lhi * 8;
                    const bf16x8 A = *(const bf16x8*)(WvT + (h * 16 + l15) * 320 + off);
                    const bf16x8 B = *(const bf16x8*)(Xbf + (tt * 16 + l15) * XS + off);
                    acc = MFMA16(A, B, acc);
                }
                const int t = tt * 16 + l15;
                const int it2 = t / 20, lt = t - it2 * 20;
#pragma unroll
                for (int r = 0; r < 4; ++r)
                    XVT[(lhi * 4 + r) * XVS + it2 * 32 + lt] = f2bf(acc[r]);
            }
        }
        __syncthreads();
        s_chunk<4>(Xbf, Qc, sacc, 0, i20, l31, hi);
        __syncthreads();

        if (w < 4) qc_et(WqAh, Xbf, Qc, 4 + w, w, l31, hi);
        __syncthreads();
        s_chunk<4>(Xbf, Qc, sacc, 128, i20, l31, hi);
        __syncthreads();

        if (w == 0 || w == 2) qc_et(WqAh, Xbf, Qc, 8 + (w >> 1), (w >> 1), l31, hi);
        __syncthreads();
        s_chunk<2>(Xbf, Qc, sacc, 256, i20, l31, hi);
        __syncthreads();

        float sv[16];
        float vmax = -1e30f;
#pragma unroll
        for (int r = 0; r < 16; ++r) {
            const int t = (r & 3) + 8 * (r >> 2) + 4 * hi;
            const float v = (t < 20) ? sacc[r] * SCALEF : -1e30f;
            sv[r] = v;
            vmax = fmaxf(vmax, v);
        }
        vmax = fmaxf(vmax, __shfl_xor(vmax, 32, 64));
        float psum = 0.f;
        float pv[16];
#pragma unroll
        for (int r = 0; r < 16; ++r) {
            const int t = (r & 3) + 8 * (r >> 2) + 4 * hi;
            const float e = (t < 20) ? __expf(sv[r] - vmax) : 0.f;
            pv[r] = e;
            psum += e;
        }
        psum += __shfl_xor(psum, 32, 64);
        const float inv = 1.f / psum;
        ushort* Pl = Qc;
        if (l31 < 20) {
            ushort* prow = Pl + (i20 + l31) * QS;
#pragma unroll
            for (int r = 0; r < 16; ++r) {
                const int t = (r & 3) + 8 * (r >> 2) + 4 * hi;
                if (t < 20) prow[t] = f2bf(pv[r] * inv);
            }
        }
        asm volatile("s_waitcnt lgkmcnt(0)" ::: "memory");
        __builtin_amdgcn_sched_barrier(0);

        unsigned plo0, phi0, plo1, phi1;
        {
            const bf16x8 A0 = *(const bf16x8*)(Pl + (i20 + l15) * QS + lhi * 8);
            const bf16x8 B0 = *(const bf16x8*)(XVT + l15 * XVS + item * 32 + lhi * 8);
            const f32x4 d0 = MFMA16(A0, B0, z4);
            const bf16x8 A1 = *(const bf16x8*)(Pl + (i20 + 16 + l15) * QS + lhi * 8);
            const f32x4 d1 = MFMA16(A1, B0, z4);
            plo0 = ((unsigned)f2bf(d0[1]) << 16) | (unsigned)f2bf(d0[0]);
            phi0 = ((unsigned)f2bf(d0[3]) << 16) | (unsigned)f2bf(d0[2]);
            plo1 = ((unsigned)f2bf(d1[1]) << 16) | (unsigned)f2bf(d1[0]);
            phi1 = ((unsigned)f2bf(d1[3]) << 16) | (unsigned)f2bf(d1[2]);
        }
#define PV_CASE(H) case H: va##H = plo0; vb##H = phi0; vc##H = plo1; vd##H = phi1; break;
        switch (h) {
            PV_CASE(0) PV_CASE(1) PV_CASE(2) PV_CASE(3)
            PV_CASE(4) PV_CASE(5) PV_CASE(6) PV_CASE(7)
            PV_CASE(8) PV_CASE(9) PV_CASE(10) PV_CASE(11)
            PV_CASE(12) PV_CASE(13) PV_CASE(14) PV_CASE(15)
        }
#undef PV_CASE
        __syncthreads();
    }

    ushort* Vlbf = Xbf;
    __syncthreads();
#pragma unroll 1
    for (int h2 = 0; h2 < 16; ++h2) {
        unsigned a = 0, b2 = 0, c = 0, d = 0;
#define UNP_CASE(H) case H: a = va##H; b2 = vb##H; c = vc##H; d = vd##H; break;
        switch (h2) {
            UNP_CASE(0) UNP_CASE(1) UNP_CASE(2) UNP_CASE(3)
            UNP_CASE(4) UNP_CASE(5) UNP_CASE(6) UNP_CASE(7)
            UNP_CASE(8) UNP_CASE(9) UNP_CASE(10) UNP_CASE(11)
            UNP_CASE(12) UNP_CASE(13) UNP_CASE(14) UNP_CASE(15)
        }
#undef UNP_CASE
        ushort* base0 = Vlbf + (i20 + lhi * 4) * VS + h2 * 16 + l15;
        base0[0 * VS] = (ushort)(a & 0xffffu);
        base0[1 * VS] = (ushort)(a >> 16);
        base0[2 * VS] = (ushort)(b2 & 0xffffu);
        base0[3 * VS] = (ushort)(b2 >> 16);
        if (lhi == 0) {
            ushort* base1 = Vlbf + (i20 + 16) * VS + h2 * 16 + l15;
            base1[0 * VS] = (ushort)(c & 0xffffu);
            base1[1 * VS] = (ushort)(c >> 16);
            base1[2 * VS] = (ushort)(d & 0xffffu);
            base1[3 * VS] = (ushort)(d >> 16);
        }
    }
    __syncthreads();

    for (int tile = w; tile < 130; tile += 8) {
        const int m = tile / 13, n = tile - m * 13;
        const int q = 16 * n + l15;
        const float bkq = (q < QDIM) ? bk[q] : 0.f;
        const float qvq = (q < QDIM) ? qv[q] : 0.f;
        f32x4 acc = z4;
#pragma unroll
        for (int ks = 0; ks < 8; ++ks) {
            const int off = ks * 32 + lhi * 8;
            const bf16x8 A = *(const bf16x8*)(Vlbf + (16 * m + l15) * VS + off);
            const bf16x8 B = *(const bf16x8*)(WkT + (16 * n + l15) * 256 + off);
            acc = MFMA16(A, B, acc);
        }
#pragma unroll
        for (int r = 0; r < 4; ++r) {
            float c = qvq * tanhf(acc[r] + bkq);
            c += __shfl_xor(c, 1, 64);
            c += __shfl_xor(c, 2, 64);
            c += __shfl_xor(c, 4, 64);
            c += __shfl_xor(c, 8, 64);
            if (l15 == 0) atomicAdd(&wrf[16 * m + lhi * 4 + r], c);
        }
    }
    __syncthreads();

    if (tid < 8) {
        const int i = tid;
        float m = -1e30f;
        for (int s = 0; s < 20; ++s) m = fmaxf(m, wrf[20 * i + s] * SCALEF);
        float sum = 0.f;
        for (int s = 0; s < 20; ++s) {
            const float e = __expf(wrf[20 * i + s] * SCALEF - m);
            wrf[20 * i + s] = e; sum += e;
        }
        const float invs = 1.f / sum;
        for (int s = 0; s < 20; ++s) wrf[20 * i + s] *= invs;
    }
    __syncthreads();

    for (int idx = tid; idx < 8 * 256; idx += 512) {
        const int i = idx >> 8, r = idx & 255;
        float s = 0.f;
#pragma unroll
        for (int t = 0; t < 20; ++t)
            s += wrf[20 * i + t] * bf2f(Vlbf[(20 * i + t) * VS + r]);
        const int gi = blockIdx.x * 8 + i;
        const int b = gi / NITEMS, it = gi - b * NITEMS;
        float* op = (it < CDD) ? (cddR + (b * CDD + it) * RP)
                               : (hisR + (b * HIS + (it - CDD)) * RP);
        op[r] = s;
    }
}

// ---------------------------------------------------------------------------
// User encoder (MFMA) — unchanged
// ---------------------------------------------------------------------------
#define US   264
#define UTS  72
#define UXVS 72
#define UVS  264

__global__ __launch_bounds__(512, 2)
void user_encoder_mfma(const float* __restrict__ hisR,
                       const ushort* __restrict__ WqnT, const ushort* __restrict__ WvnT,
                       const ushort* __restrict__ WknT,
                       const float* __restrict__ bk, const float* __restrict__ qv,
                       float* __restrict__ userR)
{
    __shared__ ushort Xu[64 * US];
    __shared__ ushort Qu[64 * US];
    __shared__ ushort XVTu[16 * UXVS];
    __shared__ ushort Atu[64 * UTS];
    __shared__ ushort Vlu[64 * UVS];
    __shared__ float  wru[64];

    const int tid = threadIdx.x;
    const int w   = tid >> 6;
    const int l15 = tid & 15;
    const int lhi = (tid >> 4) & 3;
    const f32x4 z4 = {0.f, 0.f, 0.f, 0.f};

    for (int i = tid; i < (64 * US) / 2; i += 512) ((unsigned*)Xu)[i] = 0u;
    for (int i = tid; i < (64 * UTS) / 2; i += 512) ((unsigned*)Atu)[i] = 0u;
    for (int i = tid; i < (64 * UVS) / 2; i += 512) ((unsigned*)Vlu)[i] = 0u;
    if (tid < 64) wru[tid] = 0.f;
    __syncthreads();

    const float* xp = hisR + (long)blockIdx.x * (HIS * RP);
    for (int idx = tid; idx < 50 * 64; idx += 512) {
        const int s = idx >> 6, q = idx & 63;
        const float4 v = ((const float4*)xp)[idx];
        short4v p;
        p.x = (short)f2bf(v.x); p.y = (short)f2bf(v.y);
        p.z = (short)f2bf(v.z); p.w = (short)f2bf(v.w);
        *(short4v*)(Xu + s * US + q * 4) = p;
    }
    __syncthreads();

#pragma unroll 1
    for (int h = 0; h < 16; ++h) {
        const ushort* Wqh = WqnT + h * 65536;
        for (int t8 = w; t8 < 64; t8 += 8) {
            const int et = t8 >> 2, st = t8 & 3;
            f32x4 acc = z4;
#pragma unroll
            for (int ks = 0; ks < 8; ++ks) {
                const int off = ks * 32 + lhi * 8;
                const bf16x8 A = *(const bf16x8*)(Wqh + (16 * et + l15) * 256 + off);
                const bf16x8 B = *(const bf16x8*)(Xu + (16 * st + l15) * US + off);
                acc = MFMA16(A, B, acc);
            }
            short4v p;
            p.x = (short)f2bf(acc[0]); p.y = (short)f2bf(acc[1]);
            p.z = (short)f2bf(acc[2]); p.w = (short)f2bf(acc[3]);
            *(short4v*)(Qu + (16 * st + l15) * US + 16 * et + lhi * 4) = p;
        }
        __syncthreads();

        if (w < 4) {
            f32x4 a[4] = {z4, z4, z4, z4};
#pragma unroll
            for (int ks = 0; ks < 8; ++ks) {
                const int off = ks * 32 + lhi * 8;
                const bf16x8 qa = *(const bf16x8*)(Qu + (16 * w + l15) * US + off);
#pragma unroll
                for (int n = 0; n < 4; ++n)
                    a[n] = MFMA16(qa, *(const bf16x8*)(Xu + (16 * n + l15) * US + off), a[n]);
            }
#pragma unroll
            for (int r = 0; r < 4; ++r) {
                const int srow = 16 * w + lhi * 4 + r;
                float v[4];
                float m = -1e30f;
#pragma unroll
                for (int n = 0; n < 4; ++n) {
                    const int t = 16 * n + l15;
                    v[n] = (t < HIS) ? a[n][r] * SCALEF : -1e30f;
                    m = fmaxf(m, v[n]);
                }
                m = fmaxf(m, __shfl_xor(m, 1, 64));
                m = fmaxf(m, __shfl_xor(m, 2, 64));
                m = fmaxf(m, __shfl_xor(m, 4, 64));
                m = fmaxf(m, __shfl_xor(m, 8, 64));
                float p[4]; float sum = 0.f;
#pragma unroll
                for (int n = 0; n < 4; ++n) {
                    const int t = 16 * n + l15;
                    p[n] = (t < HIS) ? __expf(v[n] - m) : 0.f;
                    sum += p[n];
                }
                sum += __shfl_xor(sum, 1, 64);
                sum += __shfl_xor(sum, 2, 64);
                sum += __shfl_xor(sum, 4, 64);
                sum += __shfl_xor(sum, 8, 64);
                const float inv = 1.f / sum;
                if (srow < HIS) {
#pragma unroll
                    for (int n = 0; n < 4; ++n)
                        Atu[srow * UTS + 16 * n + l15] = f2bf(p[n] * inv);
                }
            }
        } else {
            const int j = w - 4;
            f32x4 acc = z4;
#pragma unroll
            for (int ks = 0; ks < 8; ++ks) {
                const int off = ks * 32 + lhi * 8;
                const bf16x8 A = *(const bf16x8*)(Xu + (16 * j + l15) * US + off);
                const bf16x8 B = *(const bf16x8*)(WvnT + (h * 16 + l15) * 256 + off);
                acc = MFMA16(A, B, acc);
            }
#pragma unroll
            for (int r = 0; r < 4; ++r)
                XVTu[l15 * UXVS + 16 * j + lhi * 4 + r] = f2bf(acc[r]);
        }
        __syncthreads();

        if (w < 4) {
            f32x4 acc = z4;
#pragma unroll
            for (int ks = 0; ks < 2; ++ks) {
                const int off = ks * 32 + lhi * 8;
                const bf16x8 A = *(const bf16x8*)(Atu + (16 * w + l15) * UTS + off);
                const bf16x8 B = *(const bf16x8*)(XVTu + l15 * UXVS + off);
                acc = MFMA16(A, B, acc);
            }
#pragma unroll
            for (int r = 0; r < 4; ++r) {
                const int srow = 16 * w + lhi * 4 + r;
                if (srow < HIS) Vlu[srow * UVS + h * 16 + l15] = f2bf(acc[r]);
            }
        }
        __syncthreads();
    }

    for (int tile = w; tile < 52; tile += 8) {
        const int m = tile / 13, n = tile - m * 13;
        const int q = 16 * n + l15;
        const float bkq = (q < QDIM) ? bk[q] : 0.f;
        const float qvq = (q < QDIM) ? qv[q] : 0.f;
        f32x4 acc = z4;
#pragma unroll
        for (int ks = 0; ks < 8; ++ks) {
            const int off = ks * 32 + lhi * 8;
            const bf16x8 A = *(const bf16x8*)(Vlu + (16 * m + l15) * UVS + off);
            const bf16x8 B = *(const bf16x8*)(WknT + (16 * n + l15) * 256 + off);
            acc = MFMA16(A, B, acc);
        }
#pragma unroll
        for (int r = 0; r < 4; ++r) {
            float c = qvq * tanhf(acc[r] + bkq);
            c += __shfl_xor(c, 1, 64);
            c += __shfl_xor(c, 2, 64);
            c += __shfl_xor(c, 4, 64);
            c += __shfl_xor(c, 8, 64);
            const int srow = 16 * m + lhi * 4 + r;
            if (l15 == 0 && srow < HIS) atomicAdd(&wru[srow], c);
        }
    }
    __syncthreads();
    if (tid == 0) {
        float m = -1e30f;
        for (int s = 0; s < HIS; ++s) m = fmaxf(m, wru[s] * SCALEF);
        float sum = 0.f;
        for (int s = 0; s < HIS; ++s) {
            const float e = __expf(wru[s] * SCALEF - m);
            wru[s] = e; sum += e;
        }
        const float inv = 1.f / sum;
        for (int s = 0; s < HIS; ++s) wru[s] *= inv;
    }
    __syncthreads();
    if (tid < 256) {
        float s = 0.f;
        for (int t = 0; t < HIS; ++t) s += wru[t] * bf2f(Vlu[t * UVS + tid]);
        userR[blockIdx.x * RP + tid] = s;
    }
}

// ---------------------------------------------------------------------------
// fp32 user encoder (fallback tier) — unchanged
// ---------------------------------------------------------------------------
#define FP2 257
#define CHW 129
__global__ __launch_bounds__(512)
void user_encoder_fp32(const float* __restrict__ hisR,
                       const float* __restrict__ Wq, const float* __restrict__ Wv,
                       const float* __restrict__ Wk, const float* __restrict__ bk,
                       const float* __restrict__ qv,
                       float* __restrict__ userR)
{
    __shared__ float Xs[HIS + 1][FP2];
    __shared__ float Vl[HIS][FP2];
    __shared__ float Qcf[HIS + 1][CHW];
    __shared__ float Sm[HIS][HIS + 2];
    __shared__ float XVh[HIS][VDIM + 1];
    __shared__ float wr[HIS];

    const int tid = threadIdx.x;
    const int b = blockIdx.x;
    const float* xp = hisR + b * (HIS * RP);
    for (int i = tid; i < HIS * RP; i += 512) {
        const int s = i >> 8, f = i & 255;
        Xs[s][f] = xp[i];
    }
    __syncthreads();
    for (int h = 0; h < NH; ++h) {
        for (int chunk = 0; chunk < 2; ++chunk) {
            __syncthreads();
            const int e0 = chunk * 128;
            {
                const int sg = tid >> 7, et = tid & 127;
                const int s0 = sg * 13 - (sg == 3 ? 1 : 0);
                const float* wq = Wq + h * (RP * RP) + e0 + et;
                float acc[13] = {};
                for (int f = 0; f < RP; ++f) {
                    const float w = wq[f * RP];
#pragma unroll
                    for (int i = 0; i < 13; ++i) acc[i] += Xs[s0 + i][f] * w;
                }
#pragma unroll
                for (int i = 0; i < 13; ++i) Qcf[s0 + i][et] = acc[i];
            }
            __syncthreads();
            for (int o = tid; o < HIS * HIS; o += 512) {
                const int s = o / HIS, t = o - s * HIS;
                float acc = (chunk == 0) ? 0.f : Sm[s][t];
                for (int e = 0; e < 128; ++e) acc += Qcf[s][e] * Xs[t][e0 + e];
                Sm[s][t] = acc;
            }
        }
        __syncthreads();
        if (tid < HIS) {
            const int s = tid;
            float m = -1e30f;
            for (int t = 0; t < HIS; ++t) m = fmaxf(m, Sm[s][t]);
            m *= SCALEF;
            float sum = 0.f;
            for (int t = 0; t < HIS; ++t) { const float e = __expf(Sm[s][t] * SCALEF - m); Sm[s][t] = e; sum += e; }
            const float inv = 1.f / sum;
            for (int t = 0; t < HIS; ++t) Sm[s][t] *= inv;
        }
        for (int o = tid; o < HIS * VDIM; o += 512) {
            const int t = o >> 4, v = o & 15;
            const float* wp = Wv + h * (RP * VDIM) + v;
            float acc = 0.f;
            for (int f = 0; f < RP; ++f) acc += Xs[t][f] * wp[f * VDIM];
            XVh[t][v] = acc;
        }
        __syncthreads();
        for (int o = tid; o < HIS * VDIM; o += 512) {
            const int s = o >> 4, v = o & 15;
            float acc = 0.f;
            for (int t = 0; t < HIS; ++t) acc += Sm[s][t] * XVh[t][v];
            Vl[s][h * VDIM + v] = acc;
        }
    }
    __syncthreads();
    {
        const int s = tid >> 3, g = tid & 7;
        float part = 0.f;
        if (s < HIS) {
            for (int q = g; q < QDIM; q += 8) {
                float acc = bk[q];
                const float* wp = Wk + q;
                for (int r = 0; r < RP; ++r) acc += Vl[s][r] * wp[r * QDIM];
                part += qv[q] * tanhf(acc);
            }
        }
        part += __shfl_down(part, 1, 64);
        part += __shfl_down(part, 2, 64);
        part += __shfl_down(part, 4, 64);
        if (g == 0 && s < HIS) wr[s] = part * SCALEF;
    }
    __syncthreads();
    if (tid == 0) {
        float m = -1e30f;
        for (int s = 0; s < HIS; ++s) m = fmaxf(m, wr[s]);
        float sum = 0.f;
        for (int s = 0; s < HIS; ++s) { const float e = __expf(wr[s] - m); wr[s] = e; sum += e; }
        const float inv = 1.f / sum;
        for (int s = 0; s < HIS; ++s) wr[s] *= inv;
    }
    __syncthreads();
    float* up = userR + b * RP;
    for (int r = tid; r < RP; r += 512) {
        float acc = 0.f;
        for (int s = 0; s < HIS; ++s) acc += wr[s] * Vl[s][r];
        up[r] = acc;
    }
}

// ---------------------------------------------------------------------------
// Scores: dot + log_softmax
// ---------------------------------------------------------------------------
__global__ __launch_bounds__(64)
void score_kernel(const float* __restrict__ cddR, const float* __restrict__ userR,
                  float* __restrict__ out)
{
    const int b = blockIdx.x;
    const int lane = threadIdx.x;
    const float* u = userR + b * RP;
    float sc[CDD];
#pragma unroll
    for (int c = 0; c < CDD; ++c) {
        const float* cr = cddR + (b * CDD + c) * RP;
        float part = 0.f;
        for (int r = lane; r < RP; r += 64) part += cr[r] * u[r];
#pragma unroll
        for (int off = 32; off > 0; off >>= 1) part += __shfl_down(part, off, 64);
        sc[c] = part;
    }
    if (lane == 0) {
        float m = -1e30f;
#pragma unroll
        for (int c = 0; c < CDD; ++c) m = fmaxf(m, sc[c]);
        float sum = 0.f;
#pragma unroll
        for (int c = 0; c < CDD; ++c) sum += __expf(sc[c] - m);
        const float lse = m + logf(sum);
#pragma unroll
        for (int c = 0; c < CDD; ++c) out[b * CDD + c] = sc[c] - lse;
    }
}

extern "C" void kernel_launch(void* const* d_in, const int* in_sizes, int n_in,
                              void* d_out, int out_size, void* d_ws, size_t ws_size,
                              hipStream_t stream) {
    const int*   cddT = (const int*)d_in[0];
    const int*   hisT = (const int*)d_in[1];
    const float* E    = (const float*)d_in[2];
    const float* Wq_w = (const float*)d_in[3];
    const float* Wv_w = (const float*)d_in[4];
    const float* Wk_w = (const float*)d_in[5];
    const float* bk_w = (const float*)d_in[6];
    const float* q_w  = (const float*)d_in[7];
    const float* Wq_n = (const float*)d_in[8];
    const float* Wv_n = (const float*)d_in[9];
    const float* Wk_n = (const float*)d_in[10];
    const float* bk_n = (const float*)d_in[11];
    const float* q_n  = (const float*)d_in[12];
    float* out = (float*)d_out;

    char* wsb = (char*)d_ws;
    float*  cdd_reprs = (float*)(wsb + 0);          //  1,310,720
    float*  his_reprs = (float*)(wsb + 1310720);    // 13,107,200
    float*  user_repr = (float*)(wsb + 14417920);   //    262,144
    ushort* WqA  = (ushort*)(wsb + 14680064);       //  3,276,800
    ushort* WvT  = (ushort*)(wsb + 17956864);       //    163,840
    ushort* WkT  = (ushort*)(wsb + 18120704);       //    106,496
    ushort* WqnT = (ushort*)(wsb + 18227200);       //  2,097,152
    ushort* WvnT = (ushort*)(wsb + 20324352);       //    131,072
    ushort* WknT = (ushort*)(wsb + 20455424);       //    106,496
    ushort* EV   = (ushort*)(wsb + 20561920);       // 25,600,000 -> 46,161,920
    const bool mid  = ws_size >= 20561920ULL + 2335232ULL;
    const bool big  = ws_size >= 46161920ULL;

    prep_wqa<<<dim3(2048), 256, 0, stream>>>(Wq_w, WqA);
    transpose_pad<<<dim3(10, 1, 16), 256, 0, stream>>>(Wv_w, WvT, 300, 16, 16, 320, 16, 4800, 5120);
    transpose_pad<<<dim3(8, 7, 1), 256, 0, stream>>>(Wk_w, WkT, 256, 200, 200, 256, 208, 0, 0);
    if (mid) {
        transpose_pad<<<dim3(8, 8, 16), 256, 0, stream>>>(Wq_n, WqnT, 256, 256, 256, 256, 256, 65536, 65536);
        transpose_pad<<<dim3(8, 1, 16), 256, 0, stream>>>(Wv_n, WvnT, 256, 16, 16, 256, 16, 4096, 4096);
        transpose_pad<<<dim3(8, 7, 1), 256, 0, stream>>>(Wk_n, WknT, 256, 200, 200, 256, 208, 0, 0);
    }

    if (big) {
        prep_ev<<<dim3(782), 256, 0, stream>>>(E, WvT, EV);
        word_encoder_v7<<<dim3(NB * NITEMS / 4), dim3(256), 0, stream>>>(
            cddT, hisT, E, WqA, EV, WkT, bk_w, q_w, cdd_reprs, his_reprs);
    } else {
        word_encoder_mfma<<<dim3(NB * NITEMS / 8), dim3(512), 0, stream>>>(
            cddT, hisT, E, WqA, WvT, WkT, bk_w, q_w, cdd_reprs, his_reprs);
    }
    if (mid)
        user_encoder_mfma<<<dim3(NB), dim3(512), 0, stream>>>(
            his_reprs, WqnT, WvnT, WknT, bk_n, q_n, user_repr);
    else
        user_encoder_fp32<<<dim3(NB), dim3(512), 0, stream>>>(
            his_reprs, Wq_n, Wv_n, Wk_n, bk_n, q_n, user_repr);
    score_kernel<<<dim3(NB), dim3(64), 0, stream>>>(cdd_reprs, user_repr, out);
}

// Round 11
// 1832.711 us; speedup vs baseline: 1.4397x; 1.1603x over previous
//
#include <hip/hip_runtime.h>
#include <hip/hip_bf16.h>
#include <math.h>

#define NB 256
#define CDD 5
#define HIS 50
#define NITEMS 55
#define TT 20
#define DD 300
#define NH 16
#define VDIM 16
#define RP 256
#define QDIM 200
#define SCALEF 0.057735026918962584f   // 1/sqrt(300)

typedef __attribute__((ext_vector_type(8)))  short bf16x8;
typedef __attribute__((ext_vector_type(4)))  short short4v;
typedef __attribute__((ext_vector_type(4)))  float f32x4;
typedef __attribute__((ext_vector_type(16))) float f32x16;

#define MFMA16(a,b,c) __builtin_amdgcn_mfma_f32_16x16x32_bf16((a),(b),(c),0,0,0)
#define MFMA32(a,b,c) __builtin_amdgcn_mfma_f32_32x32x16_bf16((a),(b),(c),0,0,0)

__device__ __forceinline__ ushort f2bf(float f) {
    union { float f; unsigned u; } c; c.f = f;
    unsigned u = c.u;
    return (ushort)((u + 0x7fffu + ((u >> 16) & 1u)) >> 16);
}
__device__ __forceinline__ float bf2f(ushort h) {
    union { unsigned u; float f; } c; c.u = ((unsigned)h) << 16;
    return c.f;
}
// packed bf16 convert: low16 = bf16(a), high16 = bf16(b)
__device__ __forceinline__ unsigned cvt_pk_bf16(float a, float b) {
    unsigned r;
    asm("v_cvt_pk_bf16_f32 %0, %1, %2" : "=v"(r) : "v"(a), "v"(b));
    return r;
}

// LDS strides (elements); all ==4 mod 32 dwords -> conflict-light column reads.
#define XS  328
#define QS  136
#define VS  264
#define XVS 264   // fallback kernel's XVT stride
#define XV7 136   // v7 XVT stride

// ---------------------------------------------------------------------------
// prep_wqa: Wq[h][f 300][e 300] -> A-fragment-tiled bf16
//   WqA[h][et 10][ks 20][e_in 32][k_in 16], zero-padded.
// ---------------------------------------------------------------------------
__global__ __launch_bounds__(256)
void prep_wqa(const float* __restrict__ Wq, ushort* __restrict__ WqA)
{
    const int TOT = 16 * 102400;
    for (int idx = blockIdx.x * 256 + threadIdx.x; idx < TOT; idx += gridDim.x * 256) {
        const int h  = idx / 102400;
        int r  = idx - h * 102400;
        const int et = r / 10240;  r -= et * 10240;
        const int ks = r / 512;    r -= ks * 512;
        const int ei = r >> 4, ki = r & 15;
        const int e = et * 32 + ei, f = ks * 16 + ki;
        const float v = (e < 300 && f < 300) ? Wq[(h * 300 + f) * 300 + e] : 0.f;
        WqA[idx] = f2bf(v);
    }
}

// ---------------------------------------------------------------------------
// transpose_pad: dst[slice][c][r] = src[slice][r][c], bf16, padded
// ---------------------------------------------------------------------------
__global__ __launch_bounds__(256)
void transpose_pad(const float* __restrict__ src, ushort* __restrict__ dst,
                   int R, int C, int src_ld, int Rp, int Cv,
                   long src_ss, long dst_ss)
{
    __shared__ float T[32][33];
    const int r0 = blockIdx.x * 32;
    const int c0 = blockIdx.y * 32;
    const float* s = src + blockIdx.z * src_ss;
    ushort* d = dst + blockIdx.z * dst_ss;
    const int i = threadIdx.x >> 3;
    const int j4 = (threadIdx.x & 7) * 4;
#pragma unroll
    for (int t = 0; t < 4; ++t) {
        const int r = r0 + i, c = c0 + j4 + t;
        T[i][j4 + t] = (r < R && c < C) ? s[(long)r * src_ld + c] : 0.f;
    }
    __syncthreads();
#pragma unroll
    for (int t = 0; t < 4; ++t) {
        const int orow = c0 + i;
        const int ocol = r0 + j4 + t;
        if (orow < Cv && ocol < Rp)
            d[(long)orow * Rp + ocol] = f2bf(T[j4 + t][i]);
    }
}

// ---------------------------------------------------------------------------
// EV = E * Wv (all vocab):  EV[v][256] bf16.  64 rows per block.
// ---------------------------------------------------------------------------
__global__ __launch_bounds__(256)
void prep_ev(const float* __restrict__ E, const ushort* __restrict__ WvT,
             ushort* __restrict__ EV)
{
    __shared__ ushort Ebf[64 * XS];
    const int tid = threadIdx.x;
    const int r0 = blockIdx.x * 64;
    for (int i = tid; i < (64 * XS) / 2; i += 256) ((unsigned*)Ebf)[i] = 0u;
    __syncthreads();
    for (int idx = tid; idx < 64 * 75; idx += 256) {
        const int row = idx / 75, q = idx - row * 75;
        const int vr = r0 + row;
        if (vr < 50000) {
            const float4 v = ((const float4*)E)[(long)vr * 75 + q];
            short4v p;
            p.x = (short)f2bf(v.x); p.y = (short)f2bf(v.y);
            p.z = (short)f2bf(v.z); p.w = (short)f2bf(v.w);
            *(short4v*)(Ebf + row * XS + q * 4) = p;
        }
    }
    __syncthreads();
    const int w = tid >> 6, l15 = tid & 15, lhi = (tid >> 4) & 3;
    const f32x4 z4 = {0.f, 0.f, 0.f, 0.f};
    for (int n = 0; n < 16; ++n) {
        f32x4 acc = z4;
#pragma unroll
        for (int ks = 0; ks < 10; ++ks) {
            const int off = ks * 32 + lhi * 8;
            const bf16x8 A = *(const bf16x8*)(Ebf + (16 * w + l15) * XS + off);
            const bf16x8 B = *(const bf16x8*)(WvT + (16 * n + l15) * 320 + off);
            acc = MFMA16(A, B, acc);
        }
#pragma unroll
        for (int r = 0; r < 4; ++r) {
            const int row = r0 + 16 * w + lhi * 4 + r;
            if (row < 50000) EV[(long)row * 256 + 16 * n + l15] = f2bf(acc[r]);
        }
    }
}

__device__ __forceinline__ f32x16 zero16() {
    f32x16 z;
#pragma unroll
    for (int i = 0; i < 16; ++i) z[i] = 0.f;
    return z;
}

// ---------------------------------------------------------------------------
// qc_et3: one wave, one 32-e tile, 3 m-tiles (96 rows; m=2 writes rows<80).
// 10-deep A register pipeline + pk-convert stores.
// ---------------------------------------------------------------------------
__device__ __forceinline__ void qc_et3(const ushort* __restrict__ WqAh,
                                       const ushort* Xl, ushort* Qcl,
                                       int et, int jcol, int l31, int hi)
{
    f32x16 acc0 = zero16(), acc1 = zero16(), acc2 = zero16();
    const ushort* abase = WqAh + (et * 20) * 512 + l31 * 16 + hi * 8;
    bf16x8 Abuf[10];
#pragma unroll
    for (int i = 0; i < 10; ++i) Abuf[i] = *(const bf16x8*)(abase + i * 512);
    __builtin_amdgcn_s_setprio(1);
#pragma unroll
    for (int ks = 0; ks < 20; ++ks) {
        const bf16x8 A = Abuf[ks % 10];
        const int xoff = ks * 16 + hi * 8;
        const bf16x8 B0 = *(const bf16x8*)(Xl + (0 * 32 + l31) * XS + xoff);
        acc0 = MFMA32(A, B0, acc0);
        const bf16x8 B1 = *(const bf16x8*)(Xl + (1 * 32 + l31) * XS + xoff);
        acc1 = MFMA32(A, B1, acc1);
        const bf16x8 B2 = *(const bf16x8*)(Xl + (2 * 32 + l31) * XS + xoff);
        acc2 = MFMA32(A, B2, acc2);
        if (ks < 10) Abuf[ks] = *(const bf16x8*)(abase + (ks + 10) * 512);
    }
    __builtin_amdgcn_s_setprio(0);
#pragma unroll
    for (int m = 0; m < 3; ++m) {
        f32x16 a;
        switch (m) { case 0: a = acc0; break; case 1: a = acc1; break; default: a = acc2; break; }
        if (m == 2 && l31 >= 16) continue;   // rows >= 80 not stored
        ushort* qrow = Qcl + (32 * m + l31) * QS + jcol * 32;
#pragma unroll
        for (int g = 0; g < 4; ++g) {
            uint2 p;
            p.x = cvt_pk_bf16(a[4 * g + 0], a[4 * g + 1]);
            p.y = cvt_pk_bf16(a[4 * g + 2], a[4 * g + 3]);
            *(uint2*)(qrow + 8 * g + 4 * hi) = p;
        }
    }
}

template<int NT>
__device__ __forceinline__ void s_chunk(const ushort* Xl, const ushort* Qcl,
                                        f32x16& sacc, int ebase, int i20,
                                        int l31, int hi)
{
    const ushort* xr = Xl + (i20 + l31) * XS + ebase + hi * 8;
    const ushort* qr = Qcl + (i20 + l31) * QS + hi * 8;
    __builtin_amdgcn_s_setprio(1);
#pragma unroll
    for (int kst = 0; kst < 2 * NT; ++kst) {
        const bf16x8 A = *(const bf16x8*)(xr + kst * 16);
        const bf16x8 B = *(const bf16x8*)(qr + kst * 16);
        sacc = MFMA32(A, B, sacc);
    }
    __builtin_amdgcn_s_setprio(0);
}

// ---------------------------------------------------------------------------
// Word encoder v7: 4 items/block, 256 threads (4 waves), 79.2 KB LDS
// -> 2 independent blocks/CU. Requires EV table.
// ---------------------------------------------------------------------------
#define POOLE 39296   // ushorts: Xbf 26240 | Qc 10880 | XVT 2176

__global__ __launch_bounds__(256, 2)
void word_encoder_v7(const int* __restrict__ cddT, const int* __restrict__ hisT,
                     const float* __restrict__ E,
                     const ushort* __restrict__ WqA, const ushort* __restrict__ EV,
                     const ushort* __restrict__ WkT,
                     const float* __restrict__ bk, const float* __restrict__ qv,
                     float* __restrict__ cddR, float* __restrict__ hisR)
{
    __shared__ ushort pool[POOLE];
    __shared__ float  wrf[80];
    __shared__ int    toks[80];
    ushort* Xbf = pool;            // 80 x XS
    ushort* Qc  = pool + 26240;    // 80 x QS
    ushort* XVT = pool + 37120;    // 16 x XV7 (cols t>=20 zero; never written)

    const int tid = threadIdx.x;
    const int w   = tid >> 6;
    const int l31 = tid & 31;
    const int hi  = (tid >> 5) & 1;
    const int l15 = tid & 15;
    const int lhi = (tid >> 4) & 3;
    const f32x4 z4 = {0.f, 0.f, 0.f, 0.f};
    const int item = w;
    const int i20  = item * 20;

    for (int i = tid; i < 26240 / 2; i += 256) ((unsigned*)Xbf)[i] = 0u;
    for (int i = tid; i < 2176 / 2; i += 256) ((unsigned*)XVT)[i] = 0u;
    if (tid < 80) {
        wrf[tid] = 0.f;
        const int it_l = tid / 20, t = tid - it_l * 20;
        const int gi = blockIdx.x * 4 + it_l;
        const int b = gi / NITEMS, it = gi - b * NITEMS;
        toks[tid] = (it < CDD) ? cddT[(b * CDD + it) * TT + t]
                               : hisT[(b * HIS + (it - CDD)) * TT + t];
    }
    __syncthreads();

    // ---- embeddings -> bf16 LDS (80 rows), pk-converted ----
    for (int idx = tid; idx < 80 * 38; idx += 256) {
        const int r = idx / 38, g = idx - r * 38;
        const long base = (long)toks[r] * 300 + g * 8;
        uint2 q0, q1;
        if (g < 37) {
            const float4 v0 = *(const float4*)(E + base);
            const float4 v1 = *(const float4*)(E + base + 4);
            q0.x = cvt_pk_bf16(v0.x, v0.y); q0.y = cvt_pk_bf16(v0.z, v0.w);
            q1.x = cvt_pk_bf16(v1.x, v1.y); q1.y = cvt_pk_bf16(v1.z, v1.w);
        } else {
            const float4 v0 = *(const float4*)(E + base);
            q0.x = cvt_pk_bf16(v0.x, v0.y); q0.y = cvt_pk_bf16(v0.z, v0.w);
            q1.x = 0u; q1.y = 0u;
        }
        *(uint2*)(Xbf + r * XS + g * 8) = q0;
        *(uint2*)(Xbf + r * XS + g * 8 + 4) = q1;
    }
    __syncthreads();

    // per-item Vl packed accumulators: 16 heads x 4 u32
    unsigned va0=0,va1=0,va2=0,va3=0,va4=0,va5=0,va6=0,va7=0;
    unsigned va8=0,va9=0,va10=0,va11=0,va12=0,va13=0,va14=0,va15=0;
    unsigned vb0=0,vb1=0,vb2=0,vb3=0,vb4=0,vb5=0,vb6=0,vb7=0;
    unsigned vb8=0,vb9=0,vb10=0,vb11=0,vb12=0,vb13=0,vb14=0,vb15=0;
    unsigned vc0=0,vc1=0,vc2=0,vc3=0,vc4=0,vc5=0,vc6=0,vc7=0;
    unsigned vc8=0,vc9=0,vc10=0,vc11=0,vc12=0,vc13=0,vc14=0,vc15=0;
    unsigned vd0=0,vd1=0,vd2=0,vd3=0,vd4=0,vd5=0,vd6=0,vd7=0;
    unsigned vd8=0,vd9=0,vd10=0,vd11=0,vd12=0,vd13=0,vd14=0,vd15=0;

#pragma unroll 1
    for (int h = 0; h < 16; ++h) {
        const ushort* WqAh = WqA + h * 102400;
        f32x16 sacc = zero16();

        // ---- P0: XVT fill (tid<160) + qc chunk0 (all waves) ----
        if (tid < 160) {
            const int tok = tid >> 1, half = tid & 1;
            const int it2 = tok / 20, lt = tok - it2 * 20;
            const ushort4* src = (const ushort4*)(EV + (long)toks[tok] * 256 + h * 16 + half * 8);
            const ushort4 a = src[0], b2 = src[1];
            ushort* dst0 = XVT + (half * 8) * XV7 + it2 * 32 + lt;
            dst0[0 * XV7] = a.x;  dst0[1 * XV7] = a.y;
            dst0[2 * XV7] = a.z;  dst0[3 * XV7] = a.w;
            dst0[4 * XV7] = b2.x; dst0[5 * XV7] = b2.y;
            dst0[6 * XV7] = b2.z; dst0[7 * XV7] = b2.w;
        }
        qc_et3(WqAh, Xbf, Qc, w, w, l31, hi);
        __syncthreads();
        s_chunk<4>(Xbf, Qc, sacc, 0, i20, l31, hi);
        __syncthreads();

        qc_et3(WqAh, Xbf, Qc, 4 + w, w, l31, hi);
        __syncthreads();
        s_chunk<4>(Xbf, Qc, sacc, 128, i20, l31, hi);
        __syncthreads();

        if ((w & 1) == 0) qc_et3(WqAh, Xbf, Qc, 8 + (w >> 1), (w >> 1), l31, hi);
        __syncthreads();
        s_chunk<2>(Xbf, Qc, sacc, 256, i20, l31, hi);
        __syncthreads();

        // ---- softmax over t per s=l31, in registers ----
        float pv[16];
        float vmax = -1e30f;
#pragma unroll
        for (int r = 0; r < 16; ++r) {
            const int t = (r & 3) + 8 * (r >> 2) + 4 * hi;
            const float v = (t < 20) ? sacc[r] * SCALEF : -1e30f;
            pv[r] = v;
            vmax = fmaxf(vmax, v);
        }
        vmax = fmaxf(vmax, __shfl_xor(vmax, 32, 64));
        float psum = 0.f;
#pragma unroll
        for (int r = 0; r < 16; ++r) {
            const int t = (r & 3) + 8 * (r >> 2) + 4 * hi;
            const float e = (t < 20) ? __expf(pv[r] - vmax) : 0.f;
            pv[r] = e;
            psum += e;
        }
        psum += __shfl_xor(psum, 32, 64);
        const float inv = 1.f / psum;
        ushort* Pl = Qc;     // alias
        if (l31 < 20) {
            ushort* prow = Pl + (i20 + l31) * QS;
#pragma unroll
            for (int r = 0; r < 16; ++r) {
                const int t = (r & 3) + 8 * (r >> 2) + 4 * hi;
                if (t < 20) prow[t] = f2bf(pv[r] * inv);
            }
        }
        asm volatile("s_waitcnt lgkmcnt(0)" ::: "memory");
        __builtin_amdgcn_sched_barrier(0);

        // ---- PV: O[s][v]; Pl K-cols >=20 garbage killed by XVT zero cols ----
        unsigned plo0, phi0, plo1, phi1;
        {
            const bf16x8 A0 = *(const bf16x8*)(Pl + (i20 + l15) * QS + lhi * 8);
            const bf16x8 B0 = *(const bf16x8*)(XVT + l15 * XV7 + item * 32 + lhi * 8);
            const f32x4 d0 = MFMA16(A0, B0, z4);
            const bf16x8 A1 = *(const bf16x8*)(Pl + (i20 + 16 + l15) * QS + lhi * 8);
            const f32x4 d1 = MFMA16(A1, B0, z4);
            plo0 = ((unsigned)f2bf(d0[1]) << 16) | (unsigned)f2bf(d0[0]);
            phi0 = ((unsigned)f2bf(d0[3]) << 16) | (unsigned)f2bf(d0[2]);
            plo1 = ((unsigned)f2bf(d1[1]) << 16) | (unsigned)f2bf(d1[0]);
            phi1 = ((unsigned)f2bf(d1[3]) << 16) | (unsigned)f2bf(d1[2]);
        }
#define PV_CASE(H) case H: va##H = plo0; vb##H = phi0; vc##H = plo1; vd##H = phi1; break;
        switch (h) {
            PV_CASE(0) PV_CASE(1) PV_CASE(2) PV_CASE(3)
            PV_CASE(4) PV_CASE(5) PV_CASE(6) PV_CASE(7)
            PV_CASE(8) PV_CASE(9) PV_CASE(10) PV_CASE(11)
            PV_CASE(12) PV_CASE(13) PV_CASE(14) PV_CASE(15)
        }
#undef PV_CASE
        __syncthreads();   // head end: Qc/Pl + XVT safe to overwrite
    }

    // ---- unpack Vl -> LDS (alias Xbf) ----
    ushort* Vlbf = Xbf;
    __syncthreads();
#pragma unroll 1
    for (int h2 = 0; h2 < 16; ++h2) {
        unsigned a = 0, b2 = 0, c = 0, d = 0;
#define UNP_CASE(H) case H: a = va##H; b2 = vb##H; c = vc##H; d = vd##H; break;
        switch (h2) {
            UNP_CASE(0) UNP_CASE(1) UNP_CASE(2) UNP_CASE(3)
            UNP_CASE(4) UNP_CASE(5) UNP_CASE(6) UNP_CASE(7)
            UNP_CASE(8) UNP_CASE(9) UNP_CASE(10) UNP_CASE(11)
            UNP_CASE(12) UNP_CASE(13) UNP_CASE(14) UNP_CASE(15)
        }
#undef UNP_CASE
        ushort* base0 = Vlbf + (i20 + lhi * 4) * VS + h2 * 16 + l15;
        base0[0 * VS] = (ushort)(a & 0xffffu);
        base0[1 * VS] = (ushort)(a >> 16);
        base0[2 * VS] = (ushort)(b2 & 0xffffu);
        base0[3 * VS] = (ushort)(b2 >> 16);
        if (lhi == 0) {
            ushort* base1 = Vlbf + (i20 + 16) * VS + h2 * 16 + l15;
            base1[0 * VS] = (ushort)(c & 0xffffu);
            base1[1 * VS] = (ushort)(c >> 16);
            base1[2 * VS] = (ushort)(d & 0xffffu);
            base1[3 * VS] = (ushort)(d >> 16);
        }
    }
    __syncthreads();

    // ---- keys GEMM + tanh + qv-dot ----
    for (int tile = w; tile < 65; tile += 4) {
        const int m = tile / 13, n = tile - m * 13;
        const int q = 16 * n + l15;
        const float bkq = (q < QDIM) ? bk[q] : 0.f;
        const float qvq = (q < QDIM) ? qv[q] : 0.f;
        f32x4 acc = z4;
#pragma unroll
        for (int ks = 0; ks < 8; ++ks) {
            const int off = ks * 32 + lhi * 8;
            const bf16x8 A = *(const bf16x8*)(Vlbf + (16 * m + l15) * VS + off);
            const bf16x8 B = *(const bf16x8*)(WkT + (16 * n + l15) * 256 + off);
            acc = MFMA16(A, B, acc);
        }
#pragma unroll
        for (int r = 0; r < 4; ++r) {
            float c = qvq * tanhf(acc[r] + bkq);
            c += __shfl_xor(c, 1, 64);
            c += __shfl_xor(c, 2, 64);
            c += __shfl_xor(c, 4, 64);
            c += __shfl_xor(c, 8, 64);
            if (l15 == 0) atomicAdd(&wrf[16 * m + lhi * 4 + r], c);
        }
    }
    __syncthreads();

    if (tid < 4) {
        const int i = tid;
        float m = -1e30f;
        for (int s = 0; s < 20; ++s) m = fmaxf(m, wrf[20 * i + s] * SCALEF);
        float sum = 0.f;
        for (int s = 0; s < 20; ++s) {
            const float e = __expf(wrf[20 * i + s] * SCALEF - m);
            wrf[20 * i + s] = e; sum += e;
        }
        const float invs = 1.f / sum;
        for (int s = 0; s < 20; ++s) wrf[20 * i + s] *= invs;
    }
    __syncthreads();

    for (int idx = tid; idx < 4 * 256; idx += 256) {
        const int i = idx >> 8, r = idx & 255;
        float s = 0.f;
#pragma unroll
        for (int t = 0; t < 20; ++t)
            s += wrf[20 * i + t] * bf2f(Vlbf[(20 * i + t) * VS + r]);
        const int gi = blockIdx.x * 4 + i;
        const int b = gi / NITEMS, it = gi - b * NITEMS;
        float* op = (it < CDD) ? (cddR + (b * CDD + it) * RP)
                               : (hisR + (b * HIS + (it - CDD)) * RP);
        op[r] = s;
    }
}

// ---------------------------------------------------------------------------
// Word encoder v6 (fallback when EV table unavailable) — unchanged
// ---------------------------------------------------------------------------
__device__ __forceinline__ void qc_et(const ushort* __restrict__ WqAh,
                                      const ushort* Xl, ushort* Qcl,
                                      int et, int jcol, int l31, int hi)
{
    f32x16 acc0 = zero16(), acc1 = zero16(), acc2 = zero16(),
           acc3 = zero16(), acc4 = zero16();
    const ushort* abase = WqAh + (et * 20) * 512 + l31 * 16 + hi * 8;
    bf16x8 Abuf[5];
#pragma unroll
    for (int i = 0; i < 5; ++i) Abuf[i] = *(const bf16x8*)(abase + i * 512);
    __builtin_amdgcn_s_setprio(1);
#pragma unroll
    for (int ks = 0; ks < 20; ++ks) {
        const bf16x8 A = Abuf[ks % 5];
        const int xoff = ks * 16 + hi * 8;
        const bf16x8 B0 = *(const bf16x8*)(Xl + (0 * 32 + l31) * XS + xoff);
        acc0 = MFMA32(A, B0, acc0);
        const bf16x8 B1 = *(const bf16x8*)(Xl + (1 * 32 + l31) * XS + xoff);
        acc1 = MFMA32(A, B1, acc1);
        const bf16x8 B2 = *(const bf16x8*)(Xl + (2 * 32 + l31) * XS + xoff);
        acc2 = MFMA32(A, B2, acc2);
        const bf16x8 B3 = *(const bf16x8*)(Xl + (3 * 32 + l31) * XS + xoff);
        acc3 = MFMA32(A, B3, acc3);
        const bf16x8 B4 = *(const bf16x8*)(Xl + (4 * 32 + l31) * XS + xoff);
        acc4 = MFMA32(A, B4, acc4);
        if (ks + 5 < 20) Abuf[ks % 5] = *(const bf16x8*)(abase + (ks + 5) * 512);
    }
    __builtin_amdgcn_s_setprio(0);
#pragma unroll
    for (int m = 0; m < 5; ++m) {
        f32x16 a;
        switch (m) {
            case 0: a = acc0; break; case 1: a = acc1; break;
            case 2: a = acc2; break; case 3: a = acc3; break;
            default: a = acc4; break;
        }
        ushort* qrow = Qcl + (32 * m + l31) * QS + jcol * 32;
#pragma unroll
        for (int g = 0; g < 4; ++g) {
            short4v p;
            p.x = (short)f2bf(a[4 * g + 0]);
            p.y = (short)f2bf(a[4 * g + 1]);
            p.z = (short)f2bf(a[4 * g + 2]);
            p.w = (short)f2bf(a[4 * g + 3]);
            *(short4v*)(qrow + 8 * g + 4 * hi) = p;
        }
    }
}

__global__ __launch_bounds__(512, 2)
void word_encoder_mfma(const int* __restrict__ cddT, const int* __restrict__ hisT,
                       const float* __restrict__ E,
                       const ushort* __restrict__ WqA, const ushort* __restrict__ WvT,
                       const ushort* __restrict__ WkT,
                       const float* __restrict__ bk, const float* __restrict__ qv,
                       float* __restrict__ cddR, float* __restrict__ hisR)
{
    __shared__ ushort Xbf[160 * XS];
    __shared__ ushort Qc[160 * QS];
    __shared__ ushort XVT[16 * XVS];
    __shared__ ushort toks[160];
    __shared__ float  wrf[160];

    const int tid = threadIdx.x;
    const int w   = tid >> 6;
    const int l31 = tid & 31;
    const int hi  = (tid >> 5) & 1;
    const int l15 = tid & 15;
    const int lhi = (tid >> 4) & 3;
    const f32x4 z4 = {0.f, 0.f, 0.f, 0.f};

    for (int i = tid; i < (160 * XS) / 2; i += 512) ((unsigned*)Xbf)[i] = 0u;
    for (int i = tid; i < (16 * XVS) / 2; i += 512) ((unsigned*)XVT)[i] = 0u;
    if (tid < 160) {
        wrf[tid] = 0.f;
        const int it_l = tid / 20, t = tid - it_l * 20;
        const int gi = blockIdx.x * 8 + it_l;
        const int b = gi / NITEMS, it = gi - b * NITEMS;
        const int tk = (it < CDD) ? cddT[(b * CDD + it) * TT + t]
                                  : hisT[(b * HIS + (it - CDD)) * TT + t];
        toks[tid] = (ushort)tk;
    }
    __syncthreads();

    for (int idx = tid; idx < 160 * 38; idx += 512) {
        const int r = idx / 38, g = idx - r * 38;
        const long base = (long)toks[r] * 300 + g * 8;
        short4v p0, p1;
        if (g < 37) {
            const float4 v0 = *(const float4*)(E + base);
            const float4 v1 = *(const float4*)(E + base + 4);
            p0.x = (short)f2bf(v0.x); p0.y = (short)f2bf(v0.y);
            p0.z = (short)f2bf(v0.z); p0.w = (short)f2bf(v0.w);
            p1.x = (short)f2bf(v1.x); p1.y = (short)f2bf(v1.y);
            p1.z = (short)f2bf(v1.z); p1.w = (short)f2bf(v1.w);
        } else {
            const float4 v0 = *(const float4*)(E + base);
            p0.x = (short)f2bf(v0.x); p0.y = (short)f2bf(v0.y);
            p0.z = (short)f2bf(v0.z); p0.w = (short)f2bf(v0.w);
            p1.x = 0; p1.y = 0; p1.z = 0; p1.w = 0;
        }
        *(short4v*)(Xbf + r * XS + g * 8) = p0;
        *(short4v*)(Xbf + r * XS + g * 8 + 4) = p1;
    }
    __syncthreads();

    unsigned va0=0,va1=0,va2=0,va3=0,va4=0,va5=0,va6=0,va7=0;
    unsigned va8=0,va9=0,va10=0,va11=0,va12=0,va13=0,va14=0,va15=0;
    unsigned vb0=0,vb1=0,vb2=0,vb3=0,vb4=0,vb5=0,vb6=0,vb7=0;
    unsigned vb8=0,vb9=0,vb10=0,vb11=0,vb12=0,vb13=0,vb14=0,vb15=0;
    unsigned vc0=0,vc1=0,vc2=0,vc3=0,vc4=0,vc5=0,vc6=0,vc7=0;
    unsigned vc8=0,vc9=0,vc10=0,vc11=0,vc12=0,vc13=0,vc14=0,vc15=0;
    unsigned vd0=0,vd1=0,vd2=0,vd3=0,vd4=0,vd5=0,vd6=0,vd7=0;
    unsigned vd8=0,vd9=0,vd10=0,vd11=0,vd12=0,vd13=0,vd14=0,vd15=0;

    const int item = w;
    const int i20  = item * 20;

#pragma unroll 1
    for (int h = 0; h < 16; ++h) {
        const ushort* WqAh = WqA + h * 102400;
        f32x16 sacc = zero16();

        if (w < 4) {
            qc_et(WqAh, Xbf, Qc, w, w, l31, hi);
        } else {
            for (int tt = w - 4; tt < 10; tt += 4) {
                f32x4 acc = z4;
#pragma unroll
                for (int ks = 0; ks < 10; ++ks) {
                    const int off = ks * 32 + lhi * 8;
                    const bf16x8 A = *(const bf16x8*)(WvT + (h * 16 + l15) * 320 + off);
                    const bf16x8 B = *(const bf16x8*)(Xbf + (tt * 16 + l15) * XS + off);
                    acc = MFMA16(A, B, acc);
                }
                const int t = tt * 16 + l15;
                const int it2 = t / 20, lt = t - it2 * 20;
#pragma unroll
                for (int r = 0; r < 4; ++r)
                    XVT[(lhi * 4 + r) * XVS + it2 * 32 + lt] = f2bf(acc[r]);
            }
        }
        __syncthreads();
        s_chunk<4>(Xbf, Qc, sacc, 0, i20, l31, hi);
        __syncthreads();

        if (w < 4) qc_et(WqAh, Xbf, Qc, 4 + w, w, l31, hi);
        __syncthreads();
        s_chunk<4>(Xbf, Qc, sacc, 128, i20, l31, hi);
        __syncthreads();

        if (w == 0 || w == 2) qc_et(WqAh, Xbf, Qc, 8 + (w >> 1), (w >> 1), l31, hi);
        __syncthreads();
        s_chunk<2>(Xbf, Qc, sacc, 256, i20, l31, hi);
        __syncthreads();

        float sv[16];
        float vmax = -1e30f;
#pragma unroll
        for (int r = 0; r < 16; ++r) {
            const int t = (r & 3) + 8 * (r >> 2) + 4 * hi;
            const float v = (t < 20) ? sacc[r] * SCALEF : -1e30f;
            sv[r] = v;
            vmax = fmaxf(vmax, v);
        }
        vmax = fmaxf(vmax, __shfl_xor(vmax, 32, 64));
        float psum = 0.f;
        float pv[16];
#pragma unroll
        for (int r = 0; r < 16; ++r) {
            const int t = (r & 3) + 8 * (r >> 2) + 4 * hi;
            const float e = (t < 20) ? __expf(sv[r] - vmax) : 0.f;
            pv[r] = e;
            psum += e;
        }
        psum += __shfl_xor(psum, 32, 64);
        const float inv = 1.f / psum;
        ushort* Pl = Qc;
        if (l31 < 20) {
            ushort* prow = Pl + (i20 + l31) * QS;
#pragma unroll
            for (int r = 0; r < 16; ++r) {
                const int t = (r & 3) + 8 * (r >> 2) + 4 * hi;
                if (t < 20) prow[t] = f2bf(pv[r] * inv);
            }
        }
        asm volatile("s_waitcnt lgkmcnt(0)" ::: "memory");
        __builtin_amdgcn_sched_barrier(0);

        unsigned plo0, phi0, plo1, phi1;
        {
            const bf16x8 A0 = *(const bf16x8*)(Pl + (i20 + l15) * QS + lhi * 8);
            const bf16x8 B0 = *(const bf16x8*)(XVT + l15 * XVS + item * 32 + lhi * 8);
            const f32x4 d0 = MFMA16(A0, B0, z4);
            const bf16x8 A1 = *(const bf16x8*)(Pl + (i20 + 16 + l15) * QS + lhi * 8);
            const f32x4 d1 = MFMA16(A1, B0, z4);
            plo0 = ((unsigned)f2bf(d0[1]) << 16) | (unsigned)f2bf(d0[0]);
            phi0 = ((unsigned)f2bf(d0[3]) << 16) | (unsigned)f2bf(d0[2]);
            plo1 = ((unsigned)f2bf(d1[1]) << 16) | (unsigned)f2bf(d1[0]);
            phi1 = ((unsigned)f2bf(d1[3]) << 16) | (unsigned)f2bf(d1[2]);
        }
#define PV_CASE(H) case H: va##H = plo0; vb##H = phi0; vc##H = plo1; vd##H = phi1; break;
        switch (h) {
            PV_CASE(0) PV_CASE(1) PV_CASE(2) PV_CASE(3)
            PV_CASE(4) PV_CASE(5) PV_CASE(6) PV_CASE(7)
            PV_CASE(8) PV_CASE(9) PV_CASE(10) PV_CASE(11)
            PV_CASE(12) PV_CASE(13) PV_CASE(14) PV_CASE(15)
        }
#undef PV_CASE
        __syncthreads();
    }

    ushort* Vlbf = Xbf;
    __syncthreads();
#pragma unroll 1
    for (int h2 = 0; h2 < 16; ++h2) {
        unsigned a = 0, b2 = 0, c = 0, d = 0;
#define UNP_CASE(H) case H: a = va##H; b2 = vb##H; c = vc##H; d = vd##H; break;
        switch (h2) {
            UNP_CASE(0) UNP_CASE(1) UNP_CASE(2) UNP_CASE(3)
            UNP_CASE(4) UNP_CASE(5) UNP_CASE(6) UNP_CASE(7)
            UNP_CASE(8) UNP_CASE(9) UNP_CASE(10) UNP_CASE(11)
            UNP_CASE(12) UNP_CASE(13) UNP_CASE(14) UNP_CASE(15)
        }
#undef UNP_CASE
        ushort* base0 = Vlbf + (i20 + lhi * 4) * VS + h2 * 16 + l15;
        base0[0 * VS] = (ushort)(a & 0xffffu);
        base0[1 * VS] = (ushort)(a >> 16);
        base0[2 * VS] = (ushort)(b2 & 0xffffu);
        base0[3 * VS] = (ushort)(b2 >> 16);
        if (lhi == 0) {
            ushort* base1 = Vlbf + (i20 + 16) * VS + h2 * 16 + l15;
            base1[0 * VS] = (ushort)(c & 0xffffu);
            base1[1 * VS] = (ushort)(c >> 16);
            base1[2 * VS] = (ushort)(d & 0xffffu);
            base1[3 * VS] = (ushort)(d >> 16);
        }
    }
    __syncthreads();

    for (int tile = w; tile < 130; tile += 8) {
        const int m = tile / 13, n = tile - m * 13;
        const int q = 16 * n + l15;
        const float bkq = (q < QDIM) ? bk[q] : 0.f;
        const float qvq = (q < QDIM) ? qv[q] : 0.f;
        f32x4 acc = z4;
#pragma unroll
        for (int ks = 0; ks < 8; ++ks) {
            const int off = ks * 32 + lhi * 8;
            const bf16x8 A = *(const bf16x8*)(Vlbf + (16 * m + l15) * VS + off);
            const bf16x8 B = *(const bf16x8*)(WkT + (16 * n + l15) * 256 + off);
            acc = MFMA16(A, B, acc);
        }
#pragma unroll
        for (int r = 0; r < 4; ++r) {
            float c = qvq * tanhf(acc[r] + bkq);
            c += __shfl_xor(c, 1, 64);
            c += __shfl_xor(c, 2, 64);
            c += __shfl_xor(c, 4, 64);
            c += __shfl_xor(c, 8, 64);
            if (l15 == 0) atomicAdd(&wrf[16 * m + lhi * 4 + r], c);
        }
    }
    __syncthreads();

    if (tid < 8) {
        const int i = tid;
        float m = -1e30f;
        for (int s = 0; s < 20; ++s) m = fmaxf(m, wrf[20 * i + s] * SCALEF);
        float sum = 0.f;
        for (int s = 0; s < 20; ++s) {
            const float e = __expf(wrf[20 * i + s] * SCALEF - m);
            wrf[20 * i + s] = e; sum += e;
        }
        const float invs = 1.f / sum;
        for (int s = 0; s < 20; ++s) wrf[20 * i + s] *= invs;
    }
    __syncthreads();

    for (int idx = tid; idx < 8 * 256; idx += 512) {
        const int i = idx >> 8, r = idx & 255;
        float s = 0.f;
#pragma unroll
        for (int t = 0; t < 20; ++t)
            s += wrf[20 * i + t] * bf2f(Vlbf[(20 * i + t) * VS + r]);
        const int gi = blockIdx.x * 8 + i;
        const int b = gi / NITEMS, it = gi - b * NITEMS;
        float* op = (it < CDD) ? (cddR + (b * CDD + it) * RP)
                               : (hisR + (b * HIS + (it - CDD)) * RP);
        op[r] = s;
    }
}

// ---------------------------------------------------------------------------
// User encoder (MFMA) — unchanged
// ---------------------------------------------------------------------------
#define US   264
#define UTS  72
#define UXVS 72
#define UVS  264

__global__ __launch_bounds__(512, 2)
void user_encoder_mfma(const float* __restrict__ hisR,
                       const ushort* __restrict__ WqnT, const ushort* __restrict__ WvnT,
                       const ushort* __restrict__ WknT,
                       const float* __restrict__ bk, const float* __restrict__ qv,
                       float* __restrict__ userR)
{
    __shared__ ushort Xu[64 * US];
    __shared__ ushort Qu[64 * US];
    __shared__ ushort XVTu[16 * UXVS];
    __shared__ ushort Atu[64 * UTS];
    __shared__ ushort Vlu[64 * UVS];
    __shared__ float  wru[64];

    const int tid = threadIdx.x;
    const int w   = tid >> 6;
    const int l15 = tid & 15;
    const int lhi = (tid >> 4) & 3;
    const f32x4 z4 = {0.f, 0.f, 0.f, 0.f};

    for (int i = tid; i < (64 * US) / 2; i += 512) ((unsigned*)Xu)[i] = 0u;
    for (int i = tid; i < (64 * UTS) / 2; i += 512) ((unsigned*)Atu)[i] = 0u;
    for (int i = tid; i < (64 * UVS) / 2; i += 512) ((unsigned*)Vlu)[i] = 0u;
    if (tid < 64) wru[tid] = 0.f;
    __syncthreads();

    const float* xp = hisR + (long)blockIdx.x * (HIS * RP);
    for (int idx = tid; idx < 50 * 64; idx += 512) {
        const int s = idx >> 6, q = idx & 63;
        const float4 v = ((const float4*)xp)[idx];
        short4v p;
        p.x = (short)f2bf(v.x); p.y = (short)f2bf(v.y);
        p.z = (short)f2bf(v.z); p.w = (short)f2bf(v.w);
        *(short4v*)(Xu + s * US + q * 4) = p;
    }
    __syncthreads();

#pragma unroll 1
    for (int h = 0; h < 16; ++h) {
        const ushort* Wqh = WqnT + h * 65536;
        for (int t8 = w; t8 < 64; t8 += 8) {
            const int et = t8 >> 2, st = t8 & 3;
            f32x4 acc = z4;
#pragma unroll
            for (int ks = 0; ks < 8; ++ks) {
                const int off = ks * 32 + lhi * 8;
                const bf16x8 A = *(const bf16x8*)(Wqh + (16 * et + l15) * 256 + off);
                const bf16x8 B = *(const bf16x8*)(Xu + (16 * st + l15) * US + off);
                acc = MFMA16(A, B, acc);
            }
            short4v p;
            p.x = (short)f2bf(acc[0]); p.y = (short)f2bf(acc[1]);
            p.z = (short)f2bf(acc[2]); p.w = (short)f2bf(acc[3]);
            *(short4v*)(Qu + (16 * st + l15) * US + 16 * et + lhi * 4) = p;
        }
        __syncthreads();

        if (w < 4) {
            f32x4 a[4] = {z4, z4, z4, z4};
#pragma unroll
            for (int ks = 0; ks < 8; ++ks) {
                const int off = ks * 32 + lhi * 8;
                const bf16x8 qa = *(const bf16x8*)(Qu + (16 * w + l15) * US + off);
#pragma unroll
                for (int n = 0; n < 4; ++n)
                    a[n] = MFMA16(qa, *(const bf16x8*)(Xu + (16 * n + l15) * US + off), a[n]);
            }
#pragma unroll
            for (int r = 0; r < 4; ++r) {
                const int srow = 16 * w + lhi * 4 + r;
                float v[4];
                float m = -1e30f;
#pragma unroll
                for (int n = 0; n < 4; ++n) {
                    const int t = 16 * n + l15;
                    v[n] = (t < HIS) ? a[n][r] * SCALEF : -1e30f;
                    m = fmaxf(m, v[n]);
                }
                m = fmaxf(m, __shfl_xor(m, 1, 64));
                m = fmaxf(m, __shfl_xor(m, 2, 64));
                m = fmaxf(m, __shfl_xor(m, 4, 64));
                m = fmaxf(m, __shfl_xor(m, 8, 64));
                float p[4]; float sum = 0.f;
#pragma unroll
                for (int n = 0; n < 4; ++n) {
                    const int t = 16 * n + l15;
                    p[n] = (t < HIS) ? __expf(v[n] - m) : 0.f;
                    sum += p[n];
                }
                sum += __shfl_xor(sum, 1, 64);
                sum += __shfl_xor(sum, 2, 64);
                sum += __shfl_xor(sum, 4, 64);
                sum += __shfl_xor(sum, 8, 64);
                const float inv = 1.f / sum;
                if (srow < HIS) {
#pragma unroll
                    for (int n = 0; n < 4; ++n)
                        Atu[srow * UTS + 16 * n + l15] = f2bf(p[n] * inv);
                }
            }
        } else {
            const int j = w - 4;
            f32x4 acc = z4;
#pragma unroll
            for (int ks = 0; ks < 8; ++ks) {
                const int off = ks * 32 + lhi * 8;
                const bf16x8 A = *(const bf16x8*)(Xu + (16 * j + l15) * US + off);
                const bf16x8 B = *(const bf16x8*)(WvnT + (h * 16 + l15) * 256 + off);
                acc = MFMA16(A, B, acc);
            }
#pragma unroll
            for (int r = 0; r < 4; ++r)
                XVTu[l15 * UXVS + 16 * j + lhi * 4 + r] = f2bf(acc[r]);
        }
        __syncthreads();

        if (w < 4) {
            f32x4 acc = z4;
#pragma unroll
            for (int ks = 0; ks < 2; ++ks) {
                const int off = ks * 32 + lhi * 8;
                const bf16x8 A = *(const bf16x8*)(Atu + (16 * w + l15) * UTS + off);
                const bf16x8 B = *(const bf16x8*)(XVTu + l15 * UXVS + off);
                acc = MFMA16(A, B, acc);
            }
#pragma unroll
            for (int r = 0; r < 4; ++r) {
                const int srow = 16 * w + lhi * 4 + r;
                if (srow < HIS) Vlu[srow * UVS + h * 16 + l15] = f2bf(acc[r]);
            }
        }
        __syncthreads();
    }

    for (int tile = w; tile < 52; tile += 8) {
        const int m = tile / 13, n = tile - m * 13;
        const int q = 16 * n + l15;
        const float bkq = (q < QDIM) ? bk[q] : 0.f;
        const float qvq = (q < QDIM) ? qv[q] : 0.f;
        f32x4 acc = z4;
#pragma unroll
        for (int ks = 0; ks < 8; ++ks) {
            const int off = ks * 32 + lhi * 8;
            const bf16x8 A = *(const bf16x8*)(Vlu + (16 * m + l15) * UVS + off);
            const bf16x8 B = *(const bf16x8*)(WknT + (16 * n + l15) * 256 + off);
            acc = MFMA16(A, B, acc);
        }
#pragma unroll
        for (int r = 0; r < 4; ++r) {
            float c = qvq * tanhf(acc[r] + bkq);
            c += __shfl_xor(c, 1, 64);
            c += __shfl_xor(c, 2, 64);
            c += __shfl_xor(c, 4, 64);
            c += __shfl_xor(c, 8, 64);
            const int srow = 16 * m + lhi * 4 + r;
            if (l15 == 0 && srow < HIS) atomicAdd(&wru[srow], c);
        }
    }
    __syncthreads();
    if (tid == 0) {
        float m = -1e30f;
        for (int s = 0; s < HIS; ++s) m = fmaxf(m, wru[s] * SCALEF);
        float sum = 0.f;
        for (int s = 0; s < HIS; ++s) {
            const float e = __expf(wru[s] * SCALEF - m);
            wru[s] = e; sum += e;
        }
        const float inv = 1.f / sum;
        for (int s = 0; s < HIS; ++s) wru[s] *= inv;
    }
    __syncthreads();
    if (tid < 256) {
        float s = 0.f;
        for (int t = 0; t < HIS; ++t) s += wru[t] * bf2f(Vlu[t * UVS + tid]);
        userR[blockIdx.x * RP + tid] = s;
    }
}

// ---------------------------------------------------------------------------
// fp32 user encoder (fallback tier) — unchanged
// ---------------------------------------------------------------------------
#define FP2 257
#define CHW 129
__global__ __launch_bounds__(512)
void user_encoder_fp32(const float* __restrict__ hisR,
                       const float* __restrict__ Wq, const float* __restrict__ Wv,
                       const float* __restrict__ Wk, const float* __restrict__ bk,
                       const float* __restrict__ qv,
                       float* __restrict__ userR)
{
    __shared__ float Xs[HIS + 1][FP2];
    __shared__ float Vl[HIS][FP2];
    __shared__ float Qcf[HIS + 1][CHW];
    __shared__ float Sm[HIS][HIS + 2];
    __shared__ float XVh[HIS][VDIM + 1];
    __shared__ float wr[HIS];

    const int tid = threadIdx.x;
    const int b = blockIdx.x;
    const float* xp = hisR + b * (HIS * RP);
    for (int i = tid; i < HIS * RP; i += 512) {
        const int s = i >> 8, f = i & 255;
        Xs[s][f] = xp[i];
    }
    __syncthreads();
    for (int h = 0; h < NH; ++h) {
        for (int chunk = 0; chunk < 2; ++chunk) {
            __syncthreads();
            const int e0 = chunk * 128;
            {
                const int sg = tid >> 7, et = tid & 127;
                const int s0 = sg * 13 - (sg == 3 ? 1 : 0);
                const float* wq = Wq + h * (RP * RP) + e0 + et;
                float acc[13] = {};
                for (int f = 0; f < RP; ++f) {
                    const float w = wq[f * RP];
#pragma unroll
                    for (int i = 0; i < 13; ++i) acc[i] += Xs[s0 + i][f] * w;
                }
#pragma unroll
                for (int i = 0; i < 13; ++i) Qcf[s0 + i][et] = acc[i];
            }
            __syncthreads();
            for (int o = tid; o < HIS * HIS; o += 512) {
                const int s = o / HIS, t = o - s * HIS;
                float acc = (chunk == 0) ? 0.f : Sm[s][t];
                for (int e = 0; e < 128; ++e) acc += Qcf[s][e] * Xs[t][e0 + e];
                Sm[s][t] = acc;
            }
        }
        __syncthreads();
        if (tid < HIS) {
            const int s = tid;
            float m = -1e30f;
            for (int t = 0; t < HIS; ++t) m = fmaxf(m, Sm[s][t]);
            m *= SCALEF;
            float sum = 0.f;
            for (int t = 0; t < HIS; ++t) { const float e = __expf(Sm[s][t] * SCALEF - m); Sm[s][t] = e; sum += e; }
            const float inv = 1.f / sum;
            for (int t = 0; t < HIS; ++t) Sm[s][t] *= inv;
        }
        for (int o = tid; o < HIS * VDIM; o += 512) {
            const int t = o >> 4, v = o & 15;
            const float* wp = Wv + h * (RP * VDIM) + v;
            float acc = 0.f;
            for (int f = 0; f < RP; ++f) acc += Xs[t][f] * wp[f * VDIM];
            XVh[t][v] = acc;
        }
        __syncthreads();
        for (int o = tid; o < HIS * VDIM; o += 512) {
            const int s = o >> 4, v = o & 15;
            float acc = 0.f;
            for (int t = 0; t < HIS; ++t) acc += Sm[s][t] * XVh[t][v];
            Vl[s][h * VDIM + v] = acc;
        }
    }
    __syncthreads();
    {
        const int s = tid >> 3, g = tid & 7;
        float part = 0.f;
        if (s < HIS) {
            for (int q = g; q < QDIM; q += 8) {
                float acc = bk[q];
                const float* wp = Wk + q;
                for (int r = 0; r < RP; ++r) acc += Vl[s][r] * wp[r * QDIM];
                part += qv[q] * tanhf(acc);
            }
        }
        part += __shfl_down(part, 1, 64);
        part += __shfl_down(part, 2, 64);
        part += __shfl_down(part, 4, 64);
        if (g == 0 && s < HIS) wr[s] = part * SCALEF;
    }
    __syncthreads();
    if (tid == 0) {
        float m = -1e30f;
        for (int s = 0; s < HIS; ++s) m = fmaxf(m, wr[s]);
        float sum = 0.f;
        for (int s = 0; s < HIS; ++s) { const float e = __expf(wr[s] - m); wr[s] = e; sum += e; }
        const float inv = 1.f / sum;
        for (int s = 0; s < HIS; ++s) wr[s] *= inv;
    }
    __syncthreads();
    float* up = userR + b * RP;
    for (int r = tid; r < RP; r += 512) {
        float acc = 0.f;
        for (int s = 0; s < HIS; ++s) acc += wr[s] * Vl[s][r];
        up[r] = acc;
    }
}

// ---------------------------------------------------------------------------
// Scores: dot + log_softmax
// ---------------------------------------------------------------------------
__global__ __launch_bounds__(64)
void score_kernel(const float* __restrict__ cddR, const float* __restrict__ userR,
                  float* __restrict__ out)
{
    const int b = blockIdx.x;
    const int lane = threadIdx.x;
    const float* u = userR + b * RP;
    float sc[CDD];
#pragma unroll
    for (int c = 0; c < CDD; ++c) {
        const float* cr = cddR + (b * CDD + c) * RP;
        float part = 0.f;
        for (int r = lane; r < RP; r += 64) part += cr[r] * u[r];
#pragma unroll
        for (int off = 32; off > 0; off >>= 1) part += __shfl_down(part, off, 64);
        sc[c] = part;
    }
    if (lane == 0) {
        float m = -1e30f;
#pragma unroll
        for (int c = 0; c < CDD; ++c) m = fmaxf(m, sc[c]);
        float sum = 0.f;
#pragma unroll
        for (int c = 0; c < CDD; ++c) sum += __expf(sc[c] - m);
        const float lse = m + logf(sum);
#pragma unroll
        for (int c = 0; c < CDD; ++c) out[b * CDD + c] = sc[c] - lse;
    }
}

extern "C" void kernel_launch(void* const* d_in, const int* in_sizes, int n_in,
                              void* d_out, int out_size, void* d_ws, size_t ws_size,
                              hipStream_t stream) {
    const int*   cddT = (const int*)d_in[0];
    const int*   hisT = (const int*)d_in[1];
    const float* E    = (const float*)d_in[2];
    const float* Wq_w = (const float*)d_in[3];
    const float* Wv_w = (const float*)d_in[4];
    const float* Wk_w = (const float*)d_in[5];
    const float* bk_w = (const float*)d_in[6];
    const float* q_w  = (const float*)d_in[7];
    const float* Wq_n = (const float*)d_in[8];
    const float* Wv_n = (const float*)d_in[9];
    const float* Wk_n = (const float*)d_in[10];
    const float* bk_n = (const float*)d_in[11];
    const float* q_n  = (const float*)d_in[12];
    float* out = (float*)d_out;

    char* wsb = (char*)d_ws;
    float*  cdd_reprs = (float*)(wsb + 0);          //  1,310,720
    float*  his_reprs = (float*)(wsb + 1310720);    // 13,107,200
    float*  user_repr = (float*)(wsb + 14417920);   //    262,144
    ushort* WqA  = (ushort*)(wsb + 14680064);       //  3,276,800
    ushort* WvT  = (ushort*)(wsb + 17956864);       //    163,840
    ushort* WkT  = (ushort*)(wsb + 18120704);       //    106,496
    ushort* WqnT = (ushort*)(wsb + 18227200);       //  2,097,152
    ushort* WvnT = (ushort*)(wsb + 20324352);       //    131,072
    ushort* WknT = (ushort*)(wsb + 20455424);       //    106,496
    ushort* EV   = (ushort*)(wsb + 20561920);       // 25,600,000 -> 46,161,920
    const bool mid  = ws_size >= 20561920ULL + 2335232ULL;
    const bool big  = ws_size >= 46161920ULL;

    prep_wqa<<<dim3(2048), 256, 0, stream>>>(Wq_w, WqA);
    transpose_pad<<<dim3(10, 1, 16), 256, 0, stream>>>(Wv_w, WvT, 300, 16, 16, 320, 16, 4800, 5120);
    transpose_pad<<<dim3(8, 7, 1), 256, 0, stream>>>(Wk_w, WkT, 256, 200, 200, 256, 208, 0, 0);
    if (mid) {
        transpose_pad<<<dim3(8, 8, 16), 256, 0, stream>>>(Wq_n, WqnT, 256, 256, 256, 256, 256, 65536, 65536);
        transpose_pad<<<dim3(8, 1, 16), 256, 0, stream>>>(Wv_n, WvnT, 256, 16, 16, 256, 16, 4096, 4096);
        transpose_pad<<<dim3(8, 7, 1), 256, 0, stream>>>(Wk_n, WknT, 256, 200, 200, 256, 208, 0, 0);
    }

    if (big) {
        prep_ev<<<dim3(782), 256, 0, stream>>>(E, WvT, EV);
        word_encoder_v7<<<dim3(NB * NITEMS / 4), dim3(256), 0, stream>>>(
            cddT, hisT, E, WqA, EV, WkT, bk_w, q_w, cdd_reprs, his_reprs);
    } else {
        word_encoder_mfma<<<dim3(NB * NITEMS / 8), dim3(512), 0, stream>>>(
            cddT, hisT, E, WqA, WvT, WkT, bk_w, q_w, cdd_reprs, his_reprs);
    }
    if (mid)
        user_encoder_mfma<<<dim3(NB), dim3(512), 0, stream>>>(
            his_reprs, WqnT, WvnT, WknT, bk_n, q_n, user_repr);
    else
        user_encoder_fp32<<<dim3(NB), dim3(512), 0, stream>>>(
            his_reprs, Wq_n, Wv_n, Wk_n, bk_n, q_n, user_repr);
    score_kernel<<<dim3(NB), dim3(64), 0, stream>>>(cdd_reprs, user_repr, out);
}